// Round 1
// baseline (1588.670 us; speedup 1.0000x reference)
//
#include <hip/hip_runtime.h>
#include <cstdint>
#include <cstddef>

#define B_DIM 4
#define Q_DIM 300
#define P_DIM 16
#define C_DIM 256
#define NHD 8
#define DH 32
#define NLV 4
#define NPT 4
#define LQ (Q_DIM*P_DIM)      /* 4800 */
#define NROW (B_DIM*LQ)       /* 19200 */
#define LIN_TOT 21760
#define DFF 1024

// ---------------------------------------------------------------------------
// Generic fp32 NT GEMM: C[m,n] = sum_k A[m,k]*W[n,k] + bias[n] (optional ReLU)
// BM=BN=64, BK=32, 256 threads, 4x4 microtile. LDS stored k-major (As[k][m])
// so the inner-loop reads are contiguous float4 (no stride-K bank conflict).
// All M,N,K here are multiples of 64/64/32 -> no bounds checks.
// ---------------------------------------------------------------------------
template<int RELU>
__global__ __launch_bounds__(256) void gemm_nt(
    const float* __restrict__ A, const float* __restrict__ W,
    const float* __restrict__ bias, float* __restrict__ Cout,
    int M, int N, int K)
{
    __shared__ float As[32][68];
    __shared__ float Ws[32][68];
    const int bm = blockIdx.y * 64;
    const int bn = blockIdx.x * 64;
    const int tid = threadIdx.x;
    const int lr = tid >> 2;          // 0..63 row within tile
    const int lk = (tid & 3) << 3;    // 0,8,16,24 k-offset
    const int ty = tid >> 4;          // 0..15
    const int tx = tid & 15;          // 0..15
    const float* Arow = A + (size_t)(bm + lr) * K + lk;
    const float* Wrow = W + (size_t)(bn + lr) * K + lk;
    float acc[4][4] = {};
    for (int k0 = 0; k0 < K; k0 += 32) {
        float4 a0 = *(const float4*)(Arow + k0);
        float4 a1 = *(const float4*)(Arow + k0 + 4);
        float4 w0 = *(const float4*)(Wrow + k0);
        float4 w1 = *(const float4*)(Wrow + k0 + 4);
        __syncthreads();
        As[lk+0][lr]=a0.x; As[lk+1][lr]=a0.y; As[lk+2][lr]=a0.z; As[lk+3][lr]=a0.w;
        As[lk+4][lr]=a1.x; As[lk+5][lr]=a1.y; As[lk+6][lr]=a1.z; As[lk+7][lr]=a1.w;
        Ws[lk+0][lr]=w0.x; Ws[lk+1][lr]=w0.y; Ws[lk+2][lr]=w0.z; Ws[lk+3][lr]=w0.w;
        Ws[lk+4][lr]=w1.x; Ws[lk+5][lr]=w1.y; Ws[lk+6][lr]=w1.z; Ws[lk+7][lr]=w1.w;
        __syncthreads();
        #pragma unroll
        for (int kk = 0; kk < 32; kk++) {
            float4 av = *(const float4*)&As[kk][ty*4];
            float4 wv = *(const float4*)&Ws[kk][tx*4];
            acc[0][0] += av.x*wv.x; acc[0][1] += av.x*wv.y; acc[0][2] += av.x*wv.z; acc[0][3] += av.x*wv.w;
            acc[1][0] += av.y*wv.x; acc[1][1] += av.y*wv.y; acc[1][2] += av.y*wv.z; acc[1][3] += av.y*wv.w;
            acc[2][0] += av.z*wv.x; acc[2][1] += av.z*wv.y; acc[2][2] += av.z*wv.z; acc[2][3] += av.z*wv.w;
            acc[3][0] += av.w*wv.x; acc[3][1] += av.w*wv.y; acc[3][2] += av.w*wv.z; acc[3][3] += av.w*wv.w;
        }
    }
    const float4 b4 = *(const float4*)&bias[bn + tx*4];
    #pragma unroll
    for (int i = 0; i < 4; i++) {
        const int m = bm + ty*4 + i;
        float4 v;
        v.x = acc[i][0] + b4.x; v.y = acc[i][1] + b4.y;
        v.z = acc[i][2] + b4.z; v.w = acc[i][3] + b4.w;
        if (RELU) {
            v.x = fmaxf(v.x, 0.f); v.y = fmaxf(v.y, 0.f);
            v.z = fmaxf(v.z, 0.f); v.w = fmaxf(v.w, 0.f);
        }
        *(float4*)&Cout[(size_t)m * N + bn + tx*4] = v;
    }
}

// ---------------------------------------------------------------------------
// Self-attention: one block per (b,p,h). K/V (300x32) staged in LDS (pad 33).
// 256 threads = 8 groups of 32 lanes; each group handles one query row at a
// time (lane = channel d). Scores per lane over keys lane+32i; softmax via
// 32-wide shuffle reduce; PV via shuffle-broadcast of normalized p.
// LDS = 2*300*33*4 + 8*32*4 = 80,224 B -> 2 blocks/CU.
// ---------------------------------------------------------------------------
__global__ __launch_bounds__(256) void attn_kernel(
    const float* __restrict__ qkv, float* __restrict__ o)
{
    const int h  = blockIdx.x & 7;
    const int nb = blockIdx.x >> 3;
    const int b  = nb >> 4;     // P=16
    const int p  = nb & 15;
    __shared__ float Ks[Q_DIM][33];
    __shared__ float Vs[Q_DIM][33];
    __shared__ float Qs[8][32];
    const int tid  = threadIdx.x;
    const int lane = tid & 31;
    const int grp  = tid >> 5;
    const size_t rstride = (size_t)P_DIM * 768;
    const size_t base = ((size_t)b * Q_DIM * P_DIM + p) * 768 + h * 32;
    for (int k = grp; k < Q_DIM; k += 8) {
        const float* r = qkv + base + (size_t)k * rstride;
        Ks[k][lane] = r[256 + lane];
        Vs[k][lane] = r[512 + lane];
    }
    __syncthreads();
    const float scale = 0.17677669529663689f; // 1/sqrt(32)
    for (int q0 = 0; q0 < Q_DIM; q0 += 8) {
        const int q = q0 + grp;
        if (q >= Q_DIM) continue;
        Qs[grp][lane] = qkv[base + (size_t)q * rstride + lane];
        float sreg[10];
        float mx = -1e30f;
        #pragma unroll
        for (int i = 0; i < 10; i++) {
            const int k = lane + 32*i;
            float s = -1e30f;
            if (k < Q_DIM) {
                s = 0.f;
                #pragma unroll
                for (int d = 0; d < 32; d++) s += Ks[k][d] * Qs[grp][d];
                s *= scale;
            }
            sreg[i] = s;
            mx = fmaxf(mx, s);
        }
        #pragma unroll
        for (int m = 16; m >= 1; m >>= 1) mx = fmaxf(mx, __shfl_xor(mx, m, 32));
        float ssum = 0.f;
        #pragma unroll
        for (int i = 0; i < 10; i++) {
            const float e = __expf(sreg[i] - mx);  // invalid lanes -> exp(-big)=0
            sreg[i] = e;
            ssum += e;
        }
        #pragma unroll
        for (int m = 16; m >= 1; m >>= 1) ssum += __shfl_xor(ssum, m, 32);
        const float rinv = 1.0f / ssum;
        #pragma unroll
        for (int i = 0; i < 10; i++) sreg[i] *= rinv;
        float acc = 0.f;
        #pragma unroll
        for (int i = 0; i < 10; i++) {
            #pragma unroll
            for (int sl = 0; sl < 32; sl++) {
                const int k = 32*i + sl;
                if (k < Q_DIM) {
                    const float pv = __shfl(sreg[i], sl, 32);
                    acc += pv * Vs[k][lane];
                }
            }
        }
        // o layout (B,Q,P,C)
        o[((size_t)(b * Q_DIM + q) * P_DIM + p) * 256 + h * 32 + lane] = acc;
    }
}

// ---------------------------------------------------------------------------
// Fused add + LayerNorm over C=256. One block (256 thr) per row.
// ---------------------------------------------------------------------------
__global__ __launch_bounds__(256) void ln_add_kernel(
    const float* __restrict__ a, const float* __restrict__ b2,
    const float* __restrict__ g, const float* __restrict__ be,
    float* __restrict__ out)
{
    const int row = blockIdx.x;
    const int c = threadIdx.x;
    const size_t idx = (size_t)row * 256 + c;
    const float x = a[idx] + b2[idx];
    float s = x, s2 = x * x;
    #pragma unroll
    for (int m = 32; m >= 1; m >>= 1) {
        s  += __shfl_xor(s, m);
        s2 += __shfl_xor(s2, m);
    }
    __shared__ float ws1[4], ws2[4];
    const int w = threadIdx.x >> 6;
    if ((threadIdx.x & 63) == 0) { ws1[w] = s; ws2[w] = s2; }
    __syncthreads();
    s  = ws1[0] + ws1[1] + ws1[2] + ws1[3];
    s2 = ws2[0] + ws2[1] + ws2[2] + ws2[3];
    const float mean = s * (1.f/256.f);
    const float var  = s2 * (1.f/256.f) - mean * mean;
    const float r = rsqrtf(var + 1e-5f);
    out[idx] = (x - mean) * r * g[c] + be[c];
}

// ---------------------------------------------------------------------------
// query = x1 + query_pos (elementwise, float4)
// ---------------------------------------------------------------------------
__global__ __launch_bounds__(256) void add_kernel(
    const float4* __restrict__ a, const float4* __restrict__ b,
    float4* __restrict__ o, int n4)
{
    const int i = blockIdx.x * 256 + threadIdx.x;
    if (i < n4) {
        const float4 x = a[i], y = b[i];
        o[i] = make_float4(x.x+y.x, x.y+y.y, x.z+y.z, x.w+y.w);
    }
}

// ---------------------------------------------------------------------------
// MSDA sampling. Block per (b, q'); 256 threads = 8 heads x 32 lanes (lane=d).
// Per head: softmax over 16 attn logits (computed redundantly per lane, all
// broadcast loads), then 4 levels x 4 points bilinear gather. Each corner
// gather is 32 lanes reading 128B contiguous -> coalesced.
// ---------------------------------------------------------------------------
__global__ __launch_bounds__(256) void msda_kernel(
    const float* __restrict__ value,  // (B*LIN, 256)
    const float* __restrict__ offs,   // (B*4800, 256)
    const float* __restrict__ attw,   // (B*4800, 128)
    const float* __restrict__ refp,   // (B*4800, 4, 2)
    float* __restrict__ samp)         // (B*4800, 256)
{
    const int row = blockIdx.x;       // b*4800 + q'
    const int b = row / LQ;
    const int tid = threadIdx.x;
    const int h = tid >> 5, lane = tid & 31;

    const float* aw_p = attw + (size_t)row * 128 + h * 16;
    float lg[16];
    float mx = -1e30f;
    #pragma unroll
    for (int i = 0; i < 16; i++) { lg[i] = aw_p[i]; mx = fmaxf(mx, lg[i]); }
    float ssum = 0.f;
    #pragma unroll
    for (int i = 0; i < 16; i++) { lg[i] = __expf(lg[i] - mx); ssum += lg[i]; }
    const float rs = 1.0f / ssum;

    const float* ofs_p = offs + (size_t)row * 256 + h * 32;
    const float* ref_p = refp + (size_t)row * 8;
    const int Wl[4] = {128, 64, 32, 16};
    const int ST[4] = {0, 16384, 20480, 21504};
    float acc = 0.f;
    #pragma unroll
    for (int l = 0; l < 4; l++) {
        const float rx = ref_p[l*2 + 0];
        const float ry = ref_p[l*2 + 1];
        const int W = Wl[l], H = Wl[l];
        const float fW = (float)W, fH = (float)H;
        const float* vbase = value + ((size_t)b * LIN_TOT + ST[l]) * 256 + h * 32 + lane;
        #pragma unroll
        for (int pt = 0; pt < 4; pt++) {
            const float ox = ofs_p[(l*4 + pt)*2 + 0];
            const float oy = ofs_p[(l*4 + pt)*2 + 1];
            const float x = (rx + ox / fW) * fW - 0.5f;
            const float y = (ry + oy / fH) * fH - 0.5f;
            const float x0 = floorf(x), y0 = floorf(y);
            const float wx = x - x0, wy = y - y0;
            const int x0i = (int)x0, y0i = (int)y0;
            float v[4];
            #pragma unroll
            for (int cr = 0; cr < 4; cr++) {
                const int xi = x0i + (cr & 1);
                const int yi = y0i + (cr >> 1);
                const bool valid = (xi >= 0) & (xi < W) & (yi >= 0) & (yi < H);
                const int xc = min(max(xi, 0), W - 1);
                const int yc = min(max(yi, 0), H - 1);
                const float gv = vbase[(size_t)(yc * W + xc) * 256];
                v[cr] = valid ? gv : 0.f;
            }
            const float sv = (1.f-wx)*(1.f-wy)*v[0] + wx*(1.f-wy)*v[1]
                           + (1.f-wx)*wy*v[2]       + wx*wy*v[3];
            acc += lg[l*4 + pt] * rs * sv;
        }
    }
    samp[(size_t)row * 256 + h * 32 + lane] = acc;
}

// ---------------------------------------------------------------------------
// Workspace layout (floats), with lifetime-based reuse. Total 49,315,840
// floats = 197.3 MB.
//   BufA [0, 22282240):       qkv(14.7M) -> value(22.3M) -> ffn hidden(19.7M)
//   BufB [22282240, +4915200): o1 -> samp -> f2
//   BufC [27197440, +4915200): o2 -> offs
//   BufD [32112640, +4915200): x1
//   BufE [37027840, +4915200): query -> t2
//   BufF [41943040, +2457600): attw
//   BufG [44400640, +4915200): x2
// ---------------------------------------------------------------------------
extern "C" void kernel_launch(void* const* d_in, const int* in_sizes, int n_in,
                              void* d_out, int out_size, void* d_ws, size_t ws_size,
                              hipStream_t stream)
{
    const float* tgt        = (const float*)d_in[0];
    const float* query_pos  = (const float*)d_in[1];
    const float* refp       = (const float*)d_in[2];
    const float* src        = (const float*)d_in[3];
    // d_in[4] (spatial shapes), d_in[5] (level starts): compile-time constants
    const float* inproj_w   = (const float*)d_in[6];
    const float* inproj_b   = (const float*)d_in[7];
    const float* outproj_w  = (const float*)d_in[8];
    const float* outproj_b  = (const float*)d_in[9];
    const float* ln_inter_g = (const float*)d_in[10];
    const float* ln_inter_b = (const float*)d_in[11];
    const float* ln_cross_g = (const float*)d_in[12];
    const float* ln_cross_b = (const float*)d_in[13];
    const float* ln3_g      = (const float*)d_in[14];
    const float* ln3_b      = (const float*)d_in[15];
    const float* off_w      = (const float*)d_in[16];
    const float* off_b      = (const float*)d_in[17];
    const float* attw_w     = (const float*)d_in[18];
    const float* attw_b     = (const float*)d_in[19];
    const float* val_w      = (const float*)d_in[20];
    const float* val_b      = (const float*)d_in[21];
    const float* mout_w     = (const float*)d_in[22];
    const float* mout_b     = (const float*)d_in[23];
    const float* lin1_w     = (const float*)d_in[24];
    const float* lin1_b     = (const float*)d_in[25];
    const float* lin2_w     = (const float*)d_in[26];
    const float* lin2_b     = (const float*)d_in[27];

    float* ws = (float*)d_ws;
    float* qkv   = ws;                 // BufA
    float* value = ws;                 // BufA
    float* hbuf  = ws;                 // BufA
    float* o1    = ws + 22282240;      // BufB
    float* samp  = o1;
    float* f2    = o1;
    float* o2    = ws + 27197440;      // BufC
    float* offs  = o2;
    float* x1    = ws + 32112640;      // BufD
    float* query = ws + 37027840;      // BufE
    float* t2    = query;
    float* attw  = ws + 41943040;      // BufF
    float* x2    = ws + 44400640;      // BufG
    float* outp  = (float*)d_out;

    // 1) qkv = tgt @ inproj^T + b       (rows are (b,q,p) flat — layout-free)
    gemm_nt<0><<<dim3(12, 300), 256, 0, stream>>>(tgt, inproj_w, inproj_b, qkv, NROW, 768, 256);
    // 2) self-attention per (b,p,h)
    attn_kernel<<<512, 256, 0, stream>>>(qkv, o1);
    // 3) outproj
    gemm_nt<0><<<dim3(4, 300), 256, 0, stream>>>(o1, outproj_w, outproj_b, o2, NROW, 256, 256);
    // 4) x1 = LN(tgt + o2)
    ln_add_kernel<<<NROW, 256, 0, stream>>>(tgt, o2, ln_inter_g, ln_inter_b, x1);
    // 5) query = x1 + query_pos
    add_kernel<<<4800, 256, 0, stream>>>((const float4*)x1, (const float4*)query_pos,
                                         (float4*)query, NROW * 64);
    // 6) sampling offsets
    gemm_nt<0><<<dim3(4, 300), 256, 0, stream>>>(query, off_w, off_b, offs, NROW, 256, 256);
    // 7) attention-weight logits
    gemm_nt<0><<<dim3(2, 300), 256, 0, stream>>>(query, attw_w, attw_b, attw, NROW, 128, 256);
    // 8) value projection
    gemm_nt<0><<<dim3(4, 1360), 256, 0, stream>>>(src, val_w, val_b, value,
                                                  B_DIM * LIN_TOT, 256, 256);
    // 9) deformable sampling
    msda_kernel<<<NROW, 256, 0, stream>>>(value, offs, attw, refp, samp);
    // 10) output projection of MSDA
    gemm_nt<0><<<dim3(4, 300), 256, 0, stream>>>(samp, mout_w, mout_b, t2, NROW, 256, 256);
    // 11) x2 = LN(x1 + t2)
    ln_add_kernel<<<NROW, 256, 0, stream>>>(x1, t2, ln_cross_g, ln_cross_b, x2);
    // 12) FFN up + ReLU
    gemm_nt<1><<<dim3(16, 300), 256, 0, stream>>>(x2, lin1_w, lin1_b, hbuf, NROW, DFF, 256);
    // 13) FFN down
    gemm_nt<0><<<dim3(4, 300), 256, 0, stream>>>(hbuf, lin2_w, lin2_b, f2, NROW, 256, DFF);
    // 14) out = LN(x2 + f2)
    ln_add_kernel<<<NROW, 256, 0, stream>>>(x2, f2, ln3_g, ln3_b, outp);
}

// Round 2
// 1247.608 us; speedup vs baseline: 1.2734x; 1.2734x over previous
//
#include <hip/hip_runtime.h>
#include <cstdint>
#include <cstddef>

#define B_DIM 4
#define Q_DIM 300
#define P_DIM 16
#define C_DIM 256
#define NHD 8
#define DH 32
#define LQ (Q_DIM*P_DIM)      /* 4800 */
#define NROW (B_DIM*LQ)       /* 19200 */
#define LIN_TOT 21760
#define DFF 1024

// ---------------------------------------------------------------------------
// fp32 NT GEMM: C[m,n] = sum_k A[m,k]*W[n,k] + bias[n] (optional ReLU)
// BM=BN=128, BK=32, 256 threads, 8x8 microtile in split-64 pattern:
// rows {ty*4..+3, 64+ty*4..+3}, cols {tx*4..+3, 64+tx*4..+3} so every LDS
// read in the inner loop is either 16-lane broadcast or 2-way (free).
// All M,N multiples of 128; K multiple of 32 -> no bounds checks.
// ---------------------------------------------------------------------------
template<int RELU>
__global__ __launch_bounds__(256) void gemm_nt128(
    const float* __restrict__ A, const float* __restrict__ W,
    const float* __restrict__ bias, float* __restrict__ Cout,
    int M, int N, int K)
{
    __shared__ float As[32][132];
    __shared__ float Ws[32][132];
    const int bm = blockIdx.y * 128;
    const int bn = blockIdx.x * 128;
    const int tid = threadIdx.x;
    const int lr = tid >> 1;          // 0..127 row within tile
    const int lk = (tid & 1) << 4;    // 0 or 16
    const int ty = tid >> 4;          // 0..15
    const int tx = tid & 15;          // 0..15
    const float* Arow = A + (size_t)(bm + lr) * K + lk;
    const float* Wrow = W + (size_t)(bn + lr) * K + lk;
    float acc[8][8] = {};
    for (int k0 = 0; k0 < K; k0 += 32) {
        float4 a0 = *(const float4*)(Arow + k0);
        float4 a1 = *(const float4*)(Arow + k0 + 4);
        float4 a2 = *(const float4*)(Arow + k0 + 8);
        float4 a3 = *(const float4*)(Arow + k0 + 12);
        float4 w0 = *(const float4*)(Wrow + k0);
        float4 w1 = *(const float4*)(Wrow + k0 + 4);
        float4 w2 = *(const float4*)(Wrow + k0 + 8);
        float4 w3 = *(const float4*)(Wrow + k0 + 12);
        __syncthreads();
        As[lk+ 0][lr]=a0.x; As[lk+ 1][lr]=a0.y; As[lk+ 2][lr]=a0.z; As[lk+ 3][lr]=a0.w;
        As[lk+ 4][lr]=a1.x; As[lk+ 5][lr]=a1.y; As[lk+ 6][lr]=a1.z; As[lk+ 7][lr]=a1.w;
        As[lk+ 8][lr]=a2.x; As[lk+ 9][lr]=a2.y; As[lk+10][lr]=a2.z; As[lk+11][lr]=a2.w;
        As[lk+12][lr]=a3.x; As[lk+13][lr]=a3.y; As[lk+14][lr]=a3.z; As[lk+15][lr]=a3.w;
        Ws[lk+ 0][lr]=w0.x; Ws[lk+ 1][lr]=w0.y; Ws[lk+ 2][lr]=w0.z; Ws[lk+ 3][lr]=w0.w;
        Ws[lk+ 4][lr]=w1.x; Ws[lk+ 5][lr]=w1.y; Ws[lk+ 6][lr]=w1.z; Ws[lk+ 7][lr]=w1.w;
        Ws[lk+ 8][lr]=w2.x; Ws[lk+ 9][lr]=w2.y; Ws[lk+10][lr]=w2.z; Ws[lk+11][lr]=w2.w;
        Ws[lk+12][lr]=w3.x; Ws[lk+13][lr]=w3.y; Ws[lk+14][lr]=w3.z; Ws[lk+15][lr]=w3.w;
        __syncthreads();
        #pragma unroll 8
        for (int kk = 0; kk < 32; kk++) {
            float4 va0 = *(const float4*)&As[kk][ty*4];
            float4 va1 = *(const float4*)&As[kk][64 + ty*4];
            float4 vw0 = *(const float4*)&Ws[kk][tx*4];
            float4 vw1 = *(const float4*)&Ws[kk][64 + tx*4];
            float av[8] = {va0.x,va0.y,va0.z,va0.w, va1.x,va1.y,va1.z,va1.w};
            float wv[8] = {vw0.x,vw0.y,vw0.z,vw0.w, vw1.x,vw1.y,vw1.z,vw1.w};
            #pragma unroll
            for (int i = 0; i < 8; i++)
                #pragma unroll
                for (int j = 0; j < 8; j++)
                    acc[i][j] += av[i] * wv[j];
        }
    }
    const float4 b0 = *(const float4*)&bias[bn + tx*4];
    const float4 b1 = *(const float4*)&bias[bn + 64 + tx*4];
    const float bb[8] = {b0.x,b0.y,b0.z,b0.w, b1.x,b1.y,b1.z,b1.w};
    #pragma unroll
    for (int i = 0; i < 8; i++) {
        const int m = bm + (i < 4 ? ty*4 + i : 64 + ty*4 + (i-4));
        float v[8];
        #pragma unroll
        for (int j = 0; j < 8; j++) {
            v[j] = acc[i][j] + bb[j];
            if (RELU) v[j] = fmaxf(v[j], 0.f);
        }
        *(float4*)&Cout[(size_t)m * N + bn + tx*4]      = make_float4(v[0],v[1],v[2],v[3]);
        *(float4*)&Cout[(size_t)m * N + bn + 64 + tx*4] = make_float4(v[4],v[5],v[6],v[7]);
    }
}

// ---------------------------------------------------------------------------
// Flash-style self-attention. Block per (b,p,h, q-tile of 64). 256 threads,
// 4x4 score microtile (ty=row-group, tx=col-group), online softmax with
// 16-lane shuffle row-reduce, P staged through LDS for the PV product where
// each thread owns (4 rows) x (2 d-channels). LDS 43.5 KB -> 3 blocks/CU.
// ---------------------------------------------------------------------------
#define CHK 64
__global__ __launch_bounds__(256) void attn_flash(
    const float* __restrict__ qkv, float* __restrict__ o)
{
    const int qt  = blockIdx.x % 5;          // q-tile (5 x 64 covers 300)
    const int bph = blockIdx.x / 5;
    const int h = bph & 7;
    const int p = (bph >> 3) & 15;
    const int b = bph >> 7;
    __shared__ float Qs[32][68];   // d-major, pre-scaled
    __shared__ float Ks[32][68];   // d-major
    __shared__ float Vs[64][34];   // k-major
    __shared__ float Ps[64][68];   // unnormalized softmax chunk
    const int tid = threadIdx.x;
    const int ty = tid >> 4, tx = tid & 15;
    const int sr = tid >> 2;                 // staging row 0..63
    const int sd = (tid & 3) * 8;            // staging d-offset
    const size_t rstride = (size_t)P_DIM * 768;
    const size_t base = ((size_t)b * LQ + p) * 768 + h * 32;
    const float scale = 0.17677669529663689f; // 1/sqrt(32)
    {
        const int q = qt * 64 + sr;
        if (q < Q_DIM) {
            const float* r = qkv + base + (size_t)q * rstride + sd;
            #pragma unroll
            for (int t = 0; t < 8; t++) Qs[sd+t][sr] = r[t] * scale;
        } else {
            #pragma unroll
            for (int t = 0; t < 8; t++) Qs[sd+t][sr] = 0.f;
        }
    }
    float m_r[4], l_r[4], oa[4][2];
    #pragma unroll
    for (int i = 0; i < 4; i++) { m_r[i] = -1e30f; l_r[i] = 0.f; oa[i][0] = oa[i][1] = 0.f; }
    const int d0 = tx * 2;
    for (int k0 = 0; k0 < Q_DIM; k0 += CHK) {
        __syncthreads();
        {   // stage K (d-major) and V (k-major) chunk
            const int kc = k0 + sr;
            if (kc < Q_DIM) {
                const float* rk = qkv + base + (size_t)kc * rstride + 256 + sd;
                const float* rv = qkv + base + (size_t)kc * rstride + 512 + sd;
                #pragma unroll
                for (int t = 0; t < 8; t++) { Ks[sd+t][sr] = rk[t]; Vs[sr][sd+t] = rv[t]; }
            } else {
                #pragma unroll
                for (int t = 0; t < 8; t++) { Ks[sd+t][sr] = 0.f; Vs[sr][sd+t] = 0.f; }
            }
        }
        __syncthreads();
        // S = Q K^T microtile
        float s[4][4] = {};
        #pragma unroll
        for (int d = 0; d < 32; d++) {
            float4 a = *(const float4*)&Qs[d][ty*4];
            float4 w = *(const float4*)&Ks[d][tx*4];
            float a4[4] = {a.x,a.y,a.z,a.w};
            float w4[4] = {w.x,w.y,w.z,w.w};
            #pragma unroll
            for (int i = 0; i < 4; i++)
                #pragma unroll
                for (int j = 0; j < 4; j++)
                    s[i][j] += a4[i] * w4[j];
        }
        if (k0 + CHK > Q_DIM) {   // mask invalid key columns (last chunk)
            #pragma unroll
            for (int j = 0; j < 4; j++)
                if (k0 + tx*4 + j >= Q_DIM) { s[0][j] = s[1][j] = s[2][j] = s[3][j] = -1e30f; }
        }
        // online softmax per row (16 lanes share a row)
        #pragma unroll
        for (int i = 0; i < 4; i++) {
            float rmax = fmaxf(fmaxf(s[i][0], s[i][1]), fmaxf(s[i][2], s[i][3]));
            #pragma unroll
            for (int msk = 8; msk >= 1; msk >>= 1) rmax = fmaxf(rmax, __shfl_xor(rmax, msk));
            const float mnew = fmaxf(m_r[i], rmax);
            const float corr = __expf(m_r[i] - mnew);
            m_r[i] = mnew;
            float rsum = 0.f;
            #pragma unroll
            for (int j = 0; j < 4; j++) {
                const float e = __expf(s[i][j] - mnew);
                s[i][j] = e;
                rsum += e;
            }
            #pragma unroll
            for (int msk = 8; msk >= 1; msk >>= 1) rsum += __shfl_xor(rsum, msk);
            l_r[i] = l_r[i] * corr + rsum;
            oa[i][0] *= corr; oa[i][1] *= corr;
            *(float4*)&Ps[ty*4+i][tx*4] = make_float4(s[i][0], s[i][1], s[i][2], s[i][3]);
        }
        __syncthreads();
        // O += P V  (thread: 4 rows x 2 d)
        for (int k = 0; k < CHK; k += 4) {
            const float2 v0 = *(const float2*)&Vs[k  ][d0];
            const float2 v1 = *(const float2*)&Vs[k+1][d0];
            const float2 v2 = *(const float2*)&Vs[k+2][d0];
            const float2 v3 = *(const float2*)&Vs[k+3][d0];
            #pragma unroll
            for (int i = 0; i < 4; i++) {
                const float4 pv = *(const float4*)&Ps[ty*4+i][k];
                oa[i][0] += pv.x*v0.x + pv.y*v1.x + pv.z*v2.x + pv.w*v3.x;
                oa[i][1] += pv.x*v0.y + pv.y*v1.y + pv.z*v2.y + pv.w*v3.y;
            }
        }
    }
    #pragma unroll
    for (int i = 0; i < 4; i++) {
        const int q = qt * 64 + ty*4 + i;
        if (q < Q_DIM) {
            const float inv = 1.0f / l_r[i];
            float2 w; w.x = oa[i][0] * inv; w.y = oa[i][1] * inv;
            *(float2*)&o[(((size_t)b * Q_DIM + q) * P_DIM + p) * 256 + h*32 + d0] = w;
        }
    }
}

// ---------------------------------------------------------------------------
// Fused add + LayerNorm over C=256. One block (256 thr) per row.
// ---------------------------------------------------------------------------
__global__ __launch_bounds__(256) void ln_add_kernel(
    const float* __restrict__ a, const float* __restrict__ b2,
    const float* __restrict__ g, const float* __restrict__ be,
    float* __restrict__ out)
{
    const int row = blockIdx.x;
    const int c = threadIdx.x;
    const size_t idx = (size_t)row * 256 + c;
    const float x = a[idx] + b2[idx];
    float s = x, s2 = x * x;
    #pragma unroll
    for (int m = 32; m >= 1; m >>= 1) {
        s  += __shfl_xor(s, m);
        s2 += __shfl_xor(s2, m);
    }
    __shared__ float ws1[4], ws2[4];
    const int w = threadIdx.x >> 6;
    if ((threadIdx.x & 63) == 0) { ws1[w] = s; ws2[w] = s2; }
    __syncthreads();
    s  = ws1[0] + ws1[1] + ws1[2] + ws1[3];
    s2 = ws2[0] + ws2[1] + ws2[2] + ws2[3];
    const float mean = s * (1.f/256.f);
    const float var  = s2 * (1.f/256.f) - mean * mean;
    const float r = rsqrtf(var + 1e-5f);
    out[idx] = (x - mean) * r * g[c] + be[c];
}

__global__ __launch_bounds__(256) void add_kernel(
    const float4* __restrict__ a, const float4* __restrict__ b,
    float4* __restrict__ o, int n4)
{
    const int i = blockIdx.x * 256 + threadIdx.x;
    if (i < n4) {
        const float4 x = a[i], y = b[i];
        o[i] = make_float4(x.x+y.x, x.y+y.y, x.z+y.z, x.w+y.w);
    }
}

// ---------------------------------------------------------------------------
// MSDA sampling. Block per (b, q'); 256 threads = 8 heads x 32 lanes (lane=d).
// ---------------------------------------------------------------------------
__global__ __launch_bounds__(256) void msda_kernel(
    const float* __restrict__ value,  // (B*LIN, 256)
    const float* __restrict__ offs,   // (B*4800, 256)
    const float* __restrict__ attw,   // (B*4800, 128)
    const float* __restrict__ refp,   // (B*4800, 4, 2)
    float* __restrict__ samp)         // (B*4800, 256)
{
    const int row = blockIdx.x;
    const int b = row / LQ;
    const int tid = threadIdx.x;
    const int h = tid >> 5, lane = tid & 31;

    const float* aw_p = attw + (size_t)row * 128 + h * 16;
    float lg[16];
    float mx = -1e30f;
    #pragma unroll
    for (int i = 0; i < 16; i++) { lg[i] = aw_p[i]; mx = fmaxf(mx, lg[i]); }
    float ssum = 0.f;
    #pragma unroll
    for (int i = 0; i < 16; i++) { lg[i] = __expf(lg[i] - mx); ssum += lg[i]; }
    const float rs = 1.0f / ssum;

    const float* ofs_p = offs + (size_t)row * 256 + h * 32;
    const float* ref_p = refp + (size_t)row * 8;
    const int Wl[4] = {128, 64, 32, 16};
    const int ST[4] = {0, 16384, 20480, 21504};
    float acc = 0.f;
    #pragma unroll
    for (int l = 0; l < 4; l++) {
        const float rx = ref_p[l*2 + 0];
        const float ry = ref_p[l*2 + 1];
        const int W = Wl[l], H = Wl[l];
        const float fW = (float)W, fH = (float)H;
        const float* vbase = value + ((size_t)b * LIN_TOT + ST[l]) * 256 + h * 32 + lane;
        #pragma unroll
        for (int pt = 0; pt < 4; pt++) {
            const float ox = ofs_p[(l*4 + pt)*2 + 0];
            const float oy = ofs_p[(l*4 + pt)*2 + 1];
            const float x = (rx + ox / fW) * fW - 0.5f;
            const float y = (ry + oy / fH) * fH - 0.5f;
            const float x0 = floorf(x), y0 = floorf(y);
            const float wx = x - x0, wy = y - y0;
            const int x0i = (int)x0, y0i = (int)y0;
            float v[4];
            #pragma unroll
            for (int cr = 0; cr < 4; cr++) {
                const int xi = x0i + (cr & 1);
                const int yi = y0i + (cr >> 1);
                const bool valid = (xi >= 0) & (xi < W) & (yi >= 0) & (yi < H);
                const int xc = min(max(xi, 0), W - 1);
                const int yc = min(max(yi, 0), H - 1);
                const float gv = vbase[(size_t)(yc * W + xc) * 256];
                v[cr] = valid ? gv : 0.f;
            }
            const float sv = (1.f-wx)*(1.f-wy)*v[0] + wx*(1.f-wy)*v[1]
                           + (1.f-wx)*wy*v[2]       + wx*wy*v[3];
            acc += lg[l*4 + pt] * rs * sv;
        }
    }
    samp[(size_t)row * 256 + h * 32 + lane] = acc;
}

// ---------------------------------------------------------------------------
// Workspace layout identical to round 0 (lifetime reuse, 197.3 MB).
// ---------------------------------------------------------------------------
extern "C" void kernel_launch(void* const* d_in, const int* in_sizes, int n_in,
                              void* d_out, int out_size, void* d_ws, size_t ws_size,
                              hipStream_t stream)
{
    const float* tgt        = (const float*)d_in[0];
    const float* query_pos  = (const float*)d_in[1];
    const float* refp       = (const float*)d_in[2];
    const float* src        = (const float*)d_in[3];
    const float* inproj_w   = (const float*)d_in[6];
    const float* inproj_b   = (const float*)d_in[7];
    const float* outproj_w  = (const float*)d_in[8];
    const float* outproj_b  = (const float*)d_in[9];
    const float* ln_inter_g = (const float*)d_in[10];
    const float* ln_inter_b = (const float*)d_in[11];
    const float* ln_cross_g = (const float*)d_in[12];
    const float* ln_cross_b = (const float*)d_in[13];
    const float* ln3_g      = (const float*)d_in[14];
    const float* ln3_b      = (const float*)d_in[15];
    const float* off_w      = (const float*)d_in[16];
    const float* off_b      = (const float*)d_in[17];
    const float* attw_w     = (const float*)d_in[18];
    const float* attw_b     = (const float*)d_in[19];
    const float* val_w      = (const float*)d_in[20];
    const float* val_b      = (const float*)d_in[21];
    const float* mout_w     = (const float*)d_in[22];
    const float* mout_b     = (const float*)d_in[23];
    const float* lin1_w     = (const float*)d_in[24];
    const float* lin1_b     = (const float*)d_in[25];
    const float* lin2_w     = (const float*)d_in[26];
    const float* lin2_b     = (const float*)d_in[27];

    float* ws = (float*)d_ws;
    float* qkv   = ws;                 // BufA
    float* value = ws;                 // BufA
    float* hbuf  = ws;                 // BufA
    float* o1    = ws + 22282240;      // BufB
    float* samp  = o1;
    float* f2    = o1;
    float* o2    = ws + 27197440;      // BufC
    float* offs  = o2;
    float* x1    = ws + 32112640;      // BufD
    float* query = ws + 37027840;      // BufE
    float* t2    = query;
    float* attw  = ws + 41943040;      // BufF
    float* x2    = ws + 44400640;      // BufG
    float* outp  = (float*)d_out;

    // 1) qkv = tgt @ inproj^T + b
    gemm_nt128<0><<<dim3(6, 150), 256, 0, stream>>>(tgt, inproj_w, inproj_b, qkv, NROW, 768, 256);
    // 2) self-attention (flash)
    attn_flash<<<512 * 5, 256, 0, stream>>>(qkv, o1);
    // 3) outproj
    gemm_nt128<0><<<dim3(2, 150), 256, 0, stream>>>(o1, outproj_w, outproj_b, o2, NROW, 256, 256);
    // 4) x1 = LN(tgt + o2)
    ln_add_kernel<<<NROW, 256, 0, stream>>>(tgt, o2, ln_inter_g, ln_inter_b, x1);
    // 5) query = x1 + query_pos
    add_kernel<<<4800, 256, 0, stream>>>((const float4*)x1, (const float4*)query_pos,
                                         (float4*)query, NROW * 64);
    // 6) sampling offsets
    gemm_nt128<0><<<dim3(2, 150), 256, 0, stream>>>(query, off_w, off_b, offs, NROW, 256, 256);
    // 7) attention-weight logits
    gemm_nt128<0><<<dim3(1, 150), 256, 0, stream>>>(query, attw_w, attw_b, attw, NROW, 128, 256);
    // 8) value projection
    gemm_nt128<0><<<dim3(2, 680), 256, 0, stream>>>(src, val_w, val_b, value,
                                                    B_DIM * LIN_TOT, 256, 256);
    // 9) deformable sampling
    msda_kernel<<<NROW, 256, 0, stream>>>(value, offs, attw, refp, samp);
    // 10) output projection of MSDA
    gemm_nt128<0><<<dim3(2, 150), 256, 0, stream>>>(samp, mout_w, mout_b, t2, NROW, 256, 256);
    // 11) x2 = LN(x1 + t2)
    ln_add_kernel<<<NROW, 256, 0, stream>>>(x1, t2, ln_cross_g, ln_cross_b, x2);
    // 12) FFN up + ReLU
    gemm_nt128<1><<<dim3(8, 150), 256, 0, stream>>>(x2, lin1_w, lin1_b, hbuf, NROW, DFF, 256);
    // 13) FFN down
    gemm_nt128<0><<<dim3(2, 150), 256, 0, stream>>>(hbuf, lin2_w, lin2_b, f2, NROW, 256, DFF);
    // 14) out = LN(x2 + f2)
    ln_add_kernel<<<NROW, 256, 0, stream>>>(x2, f2, ln3_g, ln3_b, outp);
}

// Round 3
// 808.721 us; speedup vs baseline: 1.9644x; 1.5427x over previous
//
#include <hip/hip_runtime.h>
#include <cstdint>
#include <cstddef>

#define B_DIM 4
#define Q_DIM 300
#define P_DIM 16
#define C_DIM 256
#define NHD 8
#define DH 32
#define LQ (Q_DIM*P_DIM)      /* 4800 */
#define NROW (B_DIM*LQ)       /* 19200 */
#define LIN_TOT 21760
#define DFF 1024

typedef __attribute__((ext_vector_type(8))) short s16x8;   // 8 x bf16 (4 VGPR)
typedef __attribute__((ext_vector_type(4))) float f32x4;   // MFMA C/D frag

__device__ __forceinline__ unsigned short f2bf(float f) {
    unsigned u = __float_as_uint(f);
    u = u + 0x7FFFu + ((u >> 16) & 1u);   // round-to-nearest-even
    return (unsigned short)(u >> 16);
}

// ---------------------------------------------------------------------------
// bf16 MFMA NT GEMM: C[m,n] = sum_k A[m,k]*W[n,k] + bias[n]
// BM=128, BN=64, BK=64; 256 threads = 4 waves (2x2); per wave 64x32 output
// = 4x2 frags of 16x16, K=32 per mfma (2 sub-steps per K-step).
// A,W are fp32 in HBM, converted to bf16 during reg-staging (ABF16: A already
// bf16). LDS rows padded to 72 bf16 (144 B = 9x16B) for alignment + bank
// spread. RELU / bf16-output / fused A+A2 add variants via template.
// M % 128 == 0, N % 64 == 0, K % 64 == 0 (true for all call sites).
// ---------------------------------------------------------------------------
template<int RELU, int OBF16, int ABF16, int ADDA>
__global__ __launch_bounds__(256) void gemm_mfma(
    const void* __restrict__ Av, const float* __restrict__ A2,
    const float* __restrict__ W, const float* __restrict__ bias,
    void* __restrict__ Cv, int M, int N, int K)
{
    __shared__ unsigned short As[128 * 72];
    __shared__ unsigned short Ws[64 * 72];
    const int tid = threadIdx.x;
    const int bm = blockIdx.y * 128;
    const int bn = blockIdx.x * 64;
    // staging coords
    const int ar = tid >> 1;             // 0..127 A row
    const int ac = (tid & 1) * 32;       // A col half
    const int wr = tid >> 2;             // 0..63  W row
    const int wc = (tid & 3) * 16;       // W col quarter
    const float* Af = (const float*)Av;
    const unsigned short* Ab = (const unsigned short*)Av;
    const float* Afp = Af + (size_t)(bm + ar) * K + ac;
    const unsigned short* Abp = Ab + (size_t)(bm + ar) * K + ac;
    const float* A2p = A2 ? (A2 + (size_t)(bm + ar) * K + ac) : nullptr;
    const float* Wp  = W + (size_t)(bn + wr) * K + wc;
    // mfma coords
    const int lane = tid & 63;
    const int wid  = tid >> 6;
    const int wm = wid >> 1, wn = wid & 1;
    const int fr = lane & 15;            // frag row/col
    const int fq = lane >> 4;            // k-quarter 0..3
    f32x4 acc[4][2];
    #pragma unroll
    for (int m = 0; m < 4; m++)
        #pragma unroll
        for (int n = 0; n < 2; n++)
            acc[m][n] = (f32x4){0.f, 0.f, 0.f, 0.f};

    for (int k0 = 0; k0 < K; k0 += 64) {
        __syncthreads();
        // ---- stage A (128x64) ----
        if (ABF16) {
            #pragma unroll
            for (int j = 0; j < 4; j++)
                *(uint4*)&As[ar*72 + ac + j*8] = *(const uint4*)(Abp + k0 + j*8);
        } else {
            #pragma unroll
            for (int j = 0; j < 4; j++) {
                float4 x = *(const float4*)(Afp + k0 + j*8);
                float4 y = *(const float4*)(Afp + k0 + j*8 + 4);
                if (ADDA) {
                    float4 u = *(const float4*)(A2p + k0 + j*8);
                    float4 v = *(const float4*)(A2p + k0 + j*8 + 4);
                    x.x += u.x; x.y += u.y; x.z += u.z; x.w += u.w;
                    y.x += v.x; y.y += v.y; y.z += v.z; y.w += v.w;
                }
                union { unsigned short s[8]; uint4 v; } pk;
                pk.s[0]=f2bf(x.x); pk.s[1]=f2bf(x.y); pk.s[2]=f2bf(x.z); pk.s[3]=f2bf(x.w);
                pk.s[4]=f2bf(y.x); pk.s[5]=f2bf(y.y); pk.s[6]=f2bf(y.z); pk.s[7]=f2bf(y.w);
                *(uint4*)&As[ar*72 + ac + j*8] = pk.v;
            }
        }
        // ---- stage W (64x64) ----
        #pragma unroll
        for (int j = 0; j < 2; j++) {
            float4 x = *(const float4*)(Wp + k0 + j*8);
            float4 y = *(const float4*)(Wp + k0 + j*8 + 4);
            union { unsigned short s[8]; uint4 v; } pk;
            pk.s[0]=f2bf(x.x); pk.s[1]=f2bf(x.y); pk.s[2]=f2bf(x.z); pk.s[3]=f2bf(x.w);
            pk.s[4]=f2bf(y.x); pk.s[5]=f2bf(y.y); pk.s[6]=f2bf(y.z); pk.s[7]=f2bf(y.w);
            *(uint4*)&Ws[wr*72 + wc + j*8] = pk.v;
        }
        __syncthreads();
        // ---- 2 x (4x2) mfma ----
        #pragma unroll
        for (int ks = 0; ks < 64; ks += 32) {
            s16x8 a0 = *(const s16x8*)&As[(wm*64 +  0 + fr)*72 + ks + fq*8];
            s16x8 a1 = *(const s16x8*)&As[(wm*64 + 16 + fr)*72 + ks + fq*8];
            s16x8 a2 = *(const s16x8*)&As[(wm*64 + 32 + fr)*72 + ks + fq*8];
            s16x8 a3 = *(const s16x8*)&As[(wm*64 + 48 + fr)*72 + ks + fq*8];
            s16x8 b0 = *(const s16x8*)&Ws[(wn*32 +  0 + fr)*72 + ks + fq*8];
            s16x8 b1 = *(const s16x8*)&Ws[(wn*32 + 16 + fr)*72 + ks + fq*8];
            acc[0][0] = __builtin_amdgcn_mfma_f32_16x16x32_bf16(a0, b0, acc[0][0], 0, 0, 0);
            acc[0][1] = __builtin_amdgcn_mfma_f32_16x16x32_bf16(a0, b1, acc[0][1], 0, 0, 0);
            acc[1][0] = __builtin_amdgcn_mfma_f32_16x16x32_bf16(a1, b0, acc[1][0], 0, 0, 0);
            acc[1][1] = __builtin_amdgcn_mfma_f32_16x16x32_bf16(a1, b1, acc[1][1], 0, 0, 0);
            acc[2][0] = __builtin_amdgcn_mfma_f32_16x16x32_bf16(a2, b0, acc[2][0], 0, 0, 0);
            acc[2][1] = __builtin_amdgcn_mfma_f32_16x16x32_bf16(a2, b1, acc[2][1], 0, 0, 0);
            acc[3][0] = __builtin_amdgcn_mfma_f32_16x16x32_bf16(a3, b0, acc[3][0], 0, 0, 0);
            acc[3][1] = __builtin_amdgcn_mfma_f32_16x16x32_bf16(a3, b1, acc[3][1], 0, 0, 0);
        }
    }
    // ---- epilogue: D row = (first operand) m-index, col = (second) n-index ----
    float* Co = (float*)Cv;
    unsigned short* Cb = (unsigned short*)Cv;
    #pragma unroll
    for (int m = 0; m < 4; m++) {
        const int r0 = bm + wm*64 + m*16 + fq*4;
        #pragma unroll
        for (int n = 0; n < 2; n++) {
            const int col = bn + wn*32 + n*16 + fr;
            const float bsv = bias[col];
            #pragma unroll
            for (int j = 0; j < 4; j++) {
                float v = acc[m][n][j] + bsv;
                if (RELU) v = fmaxf(v, 0.f);
                if (OBF16) Cb[(size_t)(r0 + j) * N + col] = f2bf(v);
                else       Co[(size_t)(r0 + j) * N + col] = v;
            }
        }
    }
}

// ---------------------------------------------------------------------------
// Flash-style self-attention (unchanged from round 1, verified).
// ---------------------------------------------------------------------------
#define CHK 64
__global__ __launch_bounds__(256) void attn_flash(
    const float* __restrict__ qkv, float* __restrict__ o)
{
    const int qt  = blockIdx.x % 5;
    const int bph = blockIdx.x / 5;
    const int h = bph & 7;
    const int p = (bph >> 3) & 15;
    const int b = bph >> 7;
    __shared__ float Qs[32][68];
    __shared__ float Ks[32][68];
    __shared__ float Vs[64][34];
    __shared__ float Ps[64][68];
    const int tid = threadIdx.x;
    const int ty = tid >> 4, tx = tid & 15;
    const int sr = tid >> 2;
    const int sd = (tid & 3) * 8;
    const size_t rstride = (size_t)P_DIM * 768;
    const size_t base = ((size_t)b * LQ + p) * 768 + h * 32;
    const float scale = 0.17677669529663689f;
    {
        const int q = qt * 64 + sr;
        if (q < Q_DIM) {
            const float* r = qkv + base + (size_t)q * rstride + sd;
            #pragma unroll
            for (int t = 0; t < 8; t++) Qs[sd+t][sr] = r[t] * scale;
        } else {
            #pragma unroll
            for (int t = 0; t < 8; t++) Qs[sd+t][sr] = 0.f;
        }
    }
    float m_r[4], l_r[4], oa[4][2];
    #pragma unroll
    for (int i = 0; i < 4; i++) { m_r[i] = -1e30f; l_r[i] = 0.f; oa[i][0] = oa[i][1] = 0.f; }
    const int d0 = tx * 2;
    for (int k0 = 0; k0 < Q_DIM; k0 += CHK) {
        __syncthreads();
        {
            const int kc = k0 + sr;
            if (kc < Q_DIM) {
                const float* rk = qkv + base + (size_t)kc * rstride + 256 + sd;
                const float* rv = qkv + base + (size_t)kc * rstride + 512 + sd;
                #pragma unroll
                for (int t = 0; t < 8; t++) { Ks[sd+t][sr] = rk[t]; Vs[sr][sd+t] = rv[t]; }
            } else {
                #pragma unroll
                for (int t = 0; t < 8; t++) { Ks[sd+t][sr] = 0.f; Vs[sr][sd+t] = 0.f; }
            }
        }
        __syncthreads();
        float s[4][4] = {};
        #pragma unroll
        for (int d = 0; d < 32; d++) {
            float4 a = *(const float4*)&Qs[d][ty*4];
            float4 w = *(const float4*)&Ks[d][tx*4];
            float a4[4] = {a.x,a.y,a.z,a.w};
            float w4[4] = {w.x,w.y,w.z,w.w};
            #pragma unroll
            for (int i = 0; i < 4; i++)
                #pragma unroll
                for (int j = 0; j < 4; j++)
                    s[i][j] += a4[i] * w4[j];
        }
        if (k0 + CHK > Q_DIM) {
            #pragma unroll
            for (int j = 0; j < 4; j++)
                if (k0 + tx*4 + j >= Q_DIM) { s[0][j] = s[1][j] = s[2][j] = s[3][j] = -1e30f; }
        }
        #pragma unroll
        for (int i = 0; i < 4; i++) {
            float rmax = fmaxf(fmaxf(s[i][0], s[i][1]), fmaxf(s[i][2], s[i][3]));
            #pragma unroll
            for (int msk = 8; msk >= 1; msk >>= 1) rmax = fmaxf(rmax, __shfl_xor(rmax, msk));
            const float mnew = fmaxf(m_r[i], rmax);
            const float corr = __expf(m_r[i] - mnew);
            m_r[i] = mnew;
            float rsum = 0.f;
            #pragma unroll
            for (int j = 0; j < 4; j++) {
                const float e = __expf(s[i][j] - mnew);
                s[i][j] = e;
                rsum += e;
            }
            #pragma unroll
            for (int msk = 8; msk >= 1; msk >>= 1) rsum += __shfl_xor(rsum, msk);
            l_r[i] = l_r[i] * corr + rsum;
            oa[i][0] *= corr; oa[i][1] *= corr;
            *(float4*)&Ps[ty*4+i][tx*4] = make_float4(s[i][0], s[i][1], s[i][2], s[i][3]);
        }
        __syncthreads();
        for (int k = 0; k < CHK; k += 4) {
            const float2 v0 = *(const float2*)&Vs[k  ][d0];
            const float2 v1 = *(const float2*)&Vs[k+1][d0];
            const float2 v2 = *(const float2*)&Vs[k+2][d0];
            const float2 v3 = *(const float2*)&Vs[k+3][d0];
            #pragma unroll
            for (int i = 0; i < 4; i++) {
                const float4 pv = *(const float4*)&Ps[ty*4+i][k];
                oa[i][0] += pv.x*v0.x + pv.y*v1.x + pv.z*v2.x + pv.w*v3.x;
                oa[i][1] += pv.x*v0.y + pv.y*v1.y + pv.z*v2.y + pv.w*v3.y;
            }
        }
    }
    #pragma unroll
    for (int i = 0; i < 4; i++) {
        const int q = qt * 64 + ty*4 + i;
        if (q < Q_DIM) {
            const float inv = 1.0f / l_r[i];
            float2 w; w.x = oa[i][0] * inv; w.y = oa[i][1] * inv;
            *(float2*)&o[(((size_t)b * Q_DIM + q) * P_DIM + p) * 256 + h*32 + d0] = w;
        }
    }
}

// ---------------------------------------------------------------------------
// Fused add + LayerNorm over C=256. One block (256 thr) per row.
// ---------------------------------------------------------------------------
__global__ __launch_bounds__(256) void ln_add_kernel(
    const float* __restrict__ a, const float* __restrict__ b2,
    const float* __restrict__ g, const float* __restrict__ be,
    float* __restrict__ out)
{
    const int row = blockIdx.x;
    const int c = threadIdx.x;
    const size_t idx = (size_t)row * 256 + c;
    const float x = a[idx] + b2[idx];
    float s = x, s2 = x * x;
    #pragma unroll
    for (int m = 32; m >= 1; m >>= 1) {
        s  += __shfl_xor(s, m);
        s2 += __shfl_xor(s2, m);
    }
    __shared__ float ws1[4], ws2[4];
    const int w = threadIdx.x >> 6;
    if ((threadIdx.x & 63) == 0) { ws1[w] = s; ws2[w] = s2; }
    __syncthreads();
    s  = ws1[0] + ws1[1] + ws1[2] + ws1[3];
    s2 = ws2[0] + ws2[1] + ws2[2] + ws2[3];
    const float mean = s * (1.f/256.f);
    const float var  = s2 * (1.f/256.f) - mean * mean;
    const float r = rsqrtf(var + 1e-5f);
    out[idx] = (x - mean) * r * g[c] + be[c];
}

// ---------------------------------------------------------------------------
// MSDA sampling. offs/attw now come from the merged (B*4800, 384) buffer:
// cols 0..255 = offsets, 256..383 = attention-weight logits.
// ---------------------------------------------------------------------------
__global__ __launch_bounds__(256) void msda_kernel(
    const float* __restrict__ value,    // (B*LIN, 256)
    const float* __restrict__ offsattw, // (B*4800, 384)
    const float* __restrict__ refp,     // (B*4800, 4, 2)
    float* __restrict__ samp)           // (B*4800, 256)
{
    const int row = blockIdx.x;
    const int b = row / LQ;
    const int tid = threadIdx.x;
    const int h = tid >> 5, lane = tid & 31;

    const float* aw_p = offsattw + (size_t)row * 384 + 256 + h * 16;
    float lg[16];
    float mx = -1e30f;
    #pragma unroll
    for (int i = 0; i < 16; i++) { lg[i] = aw_p[i]; mx = fmaxf(mx, lg[i]); }
    float ssum = 0.f;
    #pragma unroll
    for (int i = 0; i < 16; i++) { lg[i] = __expf(lg[i] - mx); ssum += lg[i]; }
    const float rs = 1.0f / ssum;

    const float* ofs_p = offsattw + (size_t)row * 384 + h * 32;
    const float* ref_p = refp + (size_t)row * 8;
    const int Wl[4] = {128, 64, 32, 16};
    const int ST[4] = {0, 16384, 20480, 21504};
    float acc = 0.f;
    #pragma unroll
    for (int l = 0; l < 4; l++) {
        const float rx = ref_p[l*2 + 0];
        const float ry = ref_p[l*2 + 1];
        const int W = Wl[l], H = Wl[l];
        const float fW = (float)W, fH = (float)H;
        const float* vbase = value + ((size_t)b * LIN_TOT + ST[l]) * 256 + h * 32 + lane;
        #pragma unroll
        for (int pt = 0; pt < 4; pt++) {
            const float ox = ofs_p[(l*4 + pt)*2 + 0];
            const float oy = ofs_p[(l*4 + pt)*2 + 1];
            const float x = (rx + ox / fW) * fW - 0.5f;
            const float y = (ry + oy / fH) * fH - 0.5f;
            const float x0 = floorf(x), y0 = floorf(y);
            const float wx = x - x0, wy = y - y0;
            const int x0i = (int)x0, y0i = (int)y0;
            float v[4];
            #pragma unroll
            for (int cr = 0; cr < 4; cr++) {
                const int xi = x0i + (cr & 1);
                const int yi = y0i + (cr >> 1);
                const bool valid = (xi >= 0) & (xi < W) & (yi >= 0) & (yi < H);
                const int xc = min(max(xi, 0), W - 1);
                const int yc = min(max(yi, 0), H - 1);
                const float gv = vbase[(size_t)(yc * W + xc) * 256];
                v[cr] = valid ? gv : 0.f;
            }
            const float sv = (1.f-wx)*(1.f-wy)*v[0] + wx*(1.f-wy)*v[1]
                           + (1.f-wx)*wy*v[2]       + wx*wy*v[3];
            acc += lg[l*4 + pt] * rs * sv;
        }
    }
    samp[(size_t)row * 256 + h * 32 + lane] = acc;
}

// ---------------------------------------------------------------------------
// Workspace layout (floats), lifetime reuse, total 49,315,840 fl = 197.3 MB
// (identical footprint to the round-0 layout that fit).
//   A [0, 22282240):        qkv -> value -> hbuf(bf16, 39.3MB)
//   B [22282240,+4915200):  o1 -> samp -> f2
//   C [27197440,+4915200):  o2 -> t2
//   D [32112640,+4915200):  x1
//   E [37027840,+7372800):  offsattw (19200 x 384)
//   F [44400640,+4915200):  Wmerged+bias (head, used early) -> x2 (late)
// ---------------------------------------------------------------------------
extern "C" void kernel_launch(void* const* d_in, const int* in_sizes, int n_in,
                              void* d_out, int out_size, void* d_ws, size_t ws_size,
                              hipStream_t stream)
{
    const float* tgt        = (const float*)d_in[0];
    const float* query_pos  = (const float*)d_in[1];
    const float* refp       = (const float*)d_in[2];
    const float* src        = (const float*)d_in[3];
    const float* inproj_w   = (const float*)d_in[6];
    const float* inproj_b   = (const float*)d_in[7];
    const float* outproj_w  = (const float*)d_in[8];
    const float* outproj_b  = (const float*)d_in[9];
    const float* ln_inter_g = (const float*)d_in[10];
    const float* ln_inter_b = (const float*)d_in[11];
    const float* ln_cross_g = (const float*)d_in[12];
    const float* ln_cross_b = (const float*)d_in[13];
    const float* ln3_g      = (const float*)d_in[14];
    const float* ln3_b      = (const float*)d_in[15];
    const float* off_w      = (const float*)d_in[16];
    const float* off_b      = (const float*)d_in[17];
    const float* attw_w     = (const float*)d_in[18];
    const float* attw_b     = (const float*)d_in[19];
    const float* val_w      = (const float*)d_in[20];
    const float* val_b      = (const float*)d_in[21];
    const float* mout_w     = (const float*)d_in[22];
    const float* mout_b     = (const float*)d_in[23];
    const float* lin1_w     = (const float*)d_in[24];
    const float* lin1_b     = (const float*)d_in[25];
    const float* lin2_w     = (const float*)d_in[26];
    const float* lin2_b     = (const float*)d_in[27];

    float* ws = (float*)d_ws;
    float* qkv     = ws;                         // A
    float* value   = ws;                         // A
    unsigned short* hbuf = (unsigned short*)ws;  // A (bf16)
    float* o1      = ws + 22282240;              // B
    float* samp    = o1;
    float* f2      = o1;
    float* o2      = ws + 27197440;              // C
    float* t2      = o2;
    float* x1      = ws + 32112640;              // D
    float* offsattw= ws + 37027840;              // E
    float* Wm      = ws + 44400640;              // F head (dead before x2)
    float* Wb      = Wm + 98304;
    float* x2      = ws + 44400640;              // F
    float* outp    = (float*)d_out;

    // 0) pack merged offs|attw weights + biases (d2d async copies)
    hipMemcpyAsync(Wm,          off_w,  65536u * 4, hipMemcpyDeviceToDevice, stream);
    hipMemcpyAsync(Wm + 65536,  attw_w, 32768u * 4, hipMemcpyDeviceToDevice, stream);
    hipMemcpyAsync(Wb,          off_b,  256u * 4,   hipMemcpyDeviceToDevice, stream);
    hipMemcpyAsync(Wb + 256,    attw_b, 128u * 4,   hipMemcpyDeviceToDevice, stream);

    // 1) qkv = tgt @ inproj^T + b
    gemm_mfma<0,0,0,0><<<dim3(12,150), 256, 0, stream>>>(tgt, nullptr, inproj_w, inproj_b, qkv, NROW, 768, 256);
    // 2) self-attention (flash)
    attn_flash<<<2560, 256, 0, stream>>>(qkv, o1);
    // 3) outproj
    gemm_mfma<0,0,0,0><<<dim3(4,150), 256, 0, stream>>>(o1, nullptr, outproj_w, outproj_b, o2, NROW, 256, 256);
    // 4) x1 = LN(tgt + o2)
    ln_add_kernel<<<NROW, 256, 0, stream>>>(tgt, o2, ln_inter_g, ln_inter_b, x1);
    // 5) offs|attw = (x1 + query_pos) @ Wm^T + Wb   (fused add in staging)
    gemm_mfma<0,0,0,1><<<dim3(6,150), 256, 0, stream>>>(x1, query_pos, Wm, Wb, offsattw, NROW, 384, 256);
    // 6) value projection
    gemm_mfma<0,0,0,0><<<dim3(4,680), 256, 0, stream>>>(src, nullptr, val_w, val_b, value, B_DIM * LIN_TOT, 256, 256);
    // 7) deformable sampling
    msda_kernel<<<NROW, 256, 0, stream>>>(value, offsattw, refp, samp);
    // 8) mout
    gemm_mfma<0,0,0,0><<<dim3(4,150), 256, 0, stream>>>(samp, nullptr, mout_w, mout_b, t2, NROW, 256, 256);
    // 9) x2 = LN(x1 + t2)
    ln_add_kernel<<<NROW, 256, 0, stream>>>(x1, t2, ln_cross_g, ln_cross_b, x2);
    // 10) FFN up + ReLU -> bf16
    gemm_mfma<1,1,0,0><<<dim3(16,150), 256, 0, stream>>>(x2, nullptr, lin1_w, lin1_b, hbuf, NROW, DFF, 256);
    // 11) FFN down (A is bf16)
    gemm_mfma<0,0,1,0><<<dim3(4,150), 256, 0, stream>>>(hbuf, nullptr, lin2_w, lin2_b, f2, NROW, 256, DFF);
    // 12) out = LN(x2 + f2)
    ln_add_kernel<<<NROW, 256, 0, stream>>>(x2, f2, ln3_g, ln3_b, outp);
}

// Round 5
// 673.509 us; speedup vs baseline: 2.3588x; 1.2008x over previous
//
#include <hip/hip_runtime.h>
#include <cstdint>
#include <cstddef>

#define B_DIM 4
#define Q_DIM 300
#define P_DIM 16
#define C_DIM 256
#define NHD 8
#define DH 32
#define LQ (Q_DIM*P_DIM)      /* 4800 */
#define NROW (B_DIM*LQ)       /* 19200 */
#define LIN_TOT 21760
#define DFF 1024

typedef __attribute__((ext_vector_type(8))) short s16x8;   // 8 x bf16 (4 VGPR)
typedef __attribute__((ext_vector_type(4))) float f32x4;   // MFMA C/D frag

__device__ __forceinline__ unsigned short f2bf(float f) {
    unsigned u = __float_as_uint(f);
    u = u + 0x7FFFu + ((u >> 16) & 1u);   // round-to-nearest-even
    return (unsigned short)(u >> 16);
}
__device__ __forceinline__ float bf2f(unsigned short s) {
    return __uint_as_float(((unsigned)s) << 16);
}

// ---------------------------------------------------------------------------
// bf16 MFMA NT GEMM (unchanged structure from round 3, verified).
// ---------------------------------------------------------------------------
template<int RELU, int OBF16, int ABF16, int ADDA>
__global__ __launch_bounds__(256) void gemm_mfma(
    const void* __restrict__ Av, const float* __restrict__ A2,
    const float* __restrict__ W, const float* __restrict__ bias,
    void* __restrict__ Cv, int M, int N, int K)
{
    __shared__ unsigned short As[128 * 72];
    __shared__ unsigned short Ws[64 * 72];
    const int tid = threadIdx.x;
    const int bm = blockIdx.y * 128;
    const int bn = blockIdx.x * 64;
    const int ar = tid >> 1;
    const int ac = (tid & 1) * 32;
    const int wr = tid >> 2;
    const int wc = (tid & 3) * 16;
    const float* Af = (const float*)Av;
    const unsigned short* Ab = (const unsigned short*)Av;
    const float* Afp = Af + (size_t)(bm + ar) * K + ac;
    const unsigned short* Abp = Ab + (size_t)(bm + ar) * K + ac;
    const float* A2p = A2 ? (A2 + (size_t)(bm + ar) * K + ac) : nullptr;
    const float* Wp  = W + (size_t)(bn + wr) * K + wc;
    const int lane = tid & 63;
    const int wid  = tid >> 6;
    const int wm = wid >> 1, wn = wid & 1;
    const int fr = lane & 15;
    const int fq = lane >> 4;
    f32x4 acc[4][2];
    #pragma unroll
    for (int m = 0; m < 4; m++)
        #pragma unroll
        for (int n = 0; n < 2; n++)
            acc[m][n] = (f32x4){0.f, 0.f, 0.f, 0.f};

    for (int k0 = 0; k0 < K; k0 += 64) {
        __syncthreads();
        if (ABF16) {
            #pragma unroll
            for (int j = 0; j < 4; j++)
                *(uint4*)&As[ar*72 + ac + j*8] = *(const uint4*)(Abp + k0 + j*8);
        } else {
            #pragma unroll
            for (int j = 0; j < 4; j++) {
                float4 x = *(const float4*)(Afp + k0 + j*8);
                float4 y = *(const float4*)(Afp + k0 + j*8 + 4);
                if (ADDA) {
                    float4 u = *(const float4*)(A2p + k0 + j*8);
                    float4 v = *(const float4*)(A2p + k0 + j*8 + 4);
                    x.x += u.x; x.y += u.y; x.z += u.z; x.w += u.w;
                    y.x += v.x; y.y += v.y; y.z += v.z; y.w += v.w;
                }
                union { unsigned short s[8]; uint4 v; } pk;
                pk.s[0]=f2bf(x.x); pk.s[1]=f2bf(x.y); pk.s[2]=f2bf(x.z); pk.s[3]=f2bf(x.w);
                pk.s[4]=f2bf(y.x); pk.s[5]=f2bf(y.y); pk.s[6]=f2bf(y.z); pk.s[7]=f2bf(y.w);
                *(uint4*)&As[ar*72 + ac + j*8] = pk.v;
            }
        }
        #pragma unroll
        for (int j = 0; j < 2; j++) {
            float4 x = *(const float4*)(Wp + k0 + j*8);
            float4 y = *(const float4*)(Wp + k0 + j*8 + 4);
            union { unsigned short s[8]; uint4 v; } pk;
            pk.s[0]=f2bf(x.x); pk.s[1]=f2bf(x.y); pk.s[2]=f2bf(x.z); pk.s[3]=f2bf(x.w);
            pk.s[4]=f2bf(y.x); pk.s[5]=f2bf(y.y); pk.s[6]=f2bf(y.z); pk.s[7]=f2bf(y.w);
            *(uint4*)&Ws[wr*72 + wc + j*8] = pk.v;
        }
        __syncthreads();
        #pragma unroll
        for (int ks = 0; ks < 64; ks += 32) {
            s16x8 a0 = *(const s16x8*)&As[(wm*64 +  0 + fr)*72 + ks + fq*8];
            s16x8 a1 = *(const s16x8*)&As[(wm*64 + 16 + fr)*72 + ks + fq*8];
            s16x8 a2 = *(const s16x8*)&As[(wm*64 + 32 + fr)*72 + ks + fq*8];
            s16x8 a3 = *(const s16x8*)&As[(wm*64 + 48 + fr)*72 + ks + fq*8];
            s16x8 b0 = *(const s16x8*)&Ws[(wn*32 +  0 + fr)*72 + ks + fq*8];
            s16x8 b1 = *(const s16x8*)&Ws[(wn*32 + 16 + fr)*72 + ks + fq*8];
            acc[0][0] = __builtin_amdgcn_mfma_f32_16x16x32_bf16(a0, b0, acc[0][0], 0, 0, 0);
            acc[0][1] = __builtin_amdgcn_mfma_f32_16x16x32_bf16(a0, b1, acc[0][1], 0, 0, 0);
            acc[1][0] = __builtin_amdgcn_mfma_f32_16x16x32_bf16(a1, b0, acc[1][0], 0, 0, 0);
            acc[1][1] = __builtin_amdgcn_mfma_f32_16x16x32_bf16(a1, b1, acc[1][1], 0, 0, 0);
            acc[2][0] = __builtin_amdgcn_mfma_f32_16x16x32_bf16(a2, b0, acc[2][0], 0, 0, 0);
            acc[2][1] = __builtin_amdgcn_mfma_f32_16x16x32_bf16(a2, b1, acc[2][1], 0, 0, 0);
            acc[3][0] = __builtin_amdgcn_mfma_f32_16x16x32_bf16(a3, b0, acc[3][0], 0, 0, 0);
            acc[3][1] = __builtin_amdgcn_mfma_f32_16x16x32_bf16(a3, b1, acc[3][1], 0, 0, 0);
        }
    }
    float* Co = (float*)Cv;
    unsigned short* Cb = (unsigned short*)Cv;
    #pragma unroll
    for (int m = 0; m < 4; m++) {
        const int r0 = bm + wm*64 + m*16 + fq*4;
        #pragma unroll
        for (int n = 0; n < 2; n++) {
            const int col = bn + wn*32 + n*16 + fr;
            const float bsv = bias[col];
            #pragma unroll
            for (int j = 0; j < 4; j++) {
                float v = acc[m][n][j] + bsv;
                if (RELU) v = fmaxf(v, 0.f);
                if (OBF16) Cb[(size_t)(r0 + j) * N + col] = f2bf(v);
                else       Co[(size_t)(r0 + j) * N + col] = v;
            }
        }
    }
}

// ---------------------------------------------------------------------------
// MFMA self-attention. Block per (b,p,h); 256 thr = 4 waves.
// K (304 x 32, row-major, pad 40) and V^T (32 x 320, d-major, pad 328) staged
// once in LDS as bf16. Per wave: q-tile of 16 rows; 19 S-tiles (one
// mfma_16x16x32 each, DH=32 = one K-step), register softmax (scale folded
// into expf), P->per-wave-LDS round-trip, 10 PV K-steps x 2 d-tiles.
// LDS = 24320 + 20992 + 5120 = 50432 B -> 2 blocks/CU for the 512-block grid.
// ---------------------------------------------------------------------------
#define KS_ST 40
#define VT_ST 328
#define PB_ST 40
__global__ __launch_bounds__(256) void attn_mfma(
    const unsigned short* __restrict__ qkv, unsigned short* __restrict__ o)
{
    const int h  = blockIdx.x & 7;
    const int bp = blockIdx.x >> 3;   // b*16+p
    const int p  = bp & 15;
    const int b  = bp >> 4;
    __shared__ unsigned short Ks[304 * KS_ST];
    __shared__ unsigned short Vt[32 * VT_ST];
    __shared__ unsigned short Pb[4][16 * PB_ST];
    const int tid = threadIdx.x;
    const size_t qbase = ((size_t)b * 4800 + p) * 768 + h * 32; // + q*16*768
    // ---- stage K rows (zero-pad 300..303) ----
    for (int k = tid; k < 304; k += 256) {
        uint4 v0, v1, v2, v3;
        if (k < 300) {
            const unsigned short* src = qkv + qbase + (size_t)k * (16*768) + 256;
            v0 = *(const uint4*)(src);      v1 = *(const uint4*)(src + 8);
            v2 = *(const uint4*)(src + 16); v3 = *(const uint4*)(src + 24);
        } else {
            v0 = v1 = v2 = v3 = make_uint4(0u, 0u, 0u, 0u);
        }
        *(uint4*)&Ks[k*KS_ST +  0] = v0; *(uint4*)&Ks[k*KS_ST +  8] = v1;
        *(uint4*)&Ks[k*KS_ST + 16] = v2; *(uint4*)&Ks[k*KS_ST + 24] = v3;
    }
    // ---- stage V transposed (zero-pad keys 300..319) ----
    for (int k = tid; k < 320; k += 256) {
        union { uint4 v[4]; unsigned short s[32]; } t;
        if (k < 300) {
            const unsigned short* src = qkv + qbase + (size_t)k * (16*768) + 512;
            t.v[0] = *(const uint4*)(src);      t.v[1] = *(const uint4*)(src + 8);
            t.v[2] = *(const uint4*)(src + 16); t.v[3] = *(const uint4*)(src + 24);
        } else {
            t.v[0] = t.v[1] = t.v[2] = t.v[3] = make_uint4(0u, 0u, 0u, 0u);
        }
        #pragma unroll
        for (int d = 0; d < 32; d++) Vt[d*VT_ST + k] = t.s[d];
    }
    __syncthreads();

    const int wid = tid >> 6, lane = tid & 63;
    const int fr = lane & 15, fq = lane >> 4;
    const float scale = 0.17677669529663689f; // 1/sqrt(32)
    unsigned short* Pw = &Pb[wid][0];

    for (int qt = wid; qt < 19; qt += 4) {
        // Q-frag straight from global (bf16), reused across 19 S-tiles
        int qr = qt*16 + fr; if (qr > 299) qr = 299;
        const s16x8 aq = *(const s16x8*)(qkv + qbase + (size_t)qr * (16*768) + fq*8);
        // S strip: lane holds rows fq*4+j, col t*16+fr
        f32x4 s[19];
        #pragma unroll
        for (int t = 0; t < 19; t++) {
            s16x8 bk = *(const s16x8*)&Ks[(t*16 + fr)*KS_ST + fq*8];
            s[t] = __builtin_amdgcn_mfma_f32_16x16x32_bf16(aq, bk, (f32x4){0.f,0.f,0.f,0.f}, 0, 0, 0);
        }
        if (fr >= 12) s[18] = (f32x4){-1e30f, -1e30f, -1e30f, -1e30f}; // keys >= 300
        // softmax over 304 cols (19 in-lane x 16 fr-lanes)
        float mx[4], l[4];
        #pragma unroll
        for (int j = 0; j < 4; j++) {
            float m = s[0][j];
            #pragma unroll
            for (int t = 1; t < 19; t++) m = fmaxf(m, s[t][j]);
            #pragma unroll
            for (int msk = 1; msk < 16; msk <<= 1) m = fmaxf(m, __shfl_xor(m, msk));
            mx[j] = m;
        }
        #pragma unroll
        for (int j = 0; j < 4; j++) {
            float sum = 0.f;
            #pragma unroll
            for (int t = 0; t < 19; t++) {
                const float e = __expf((s[t][j] - mx[j]) * scale);
                s[t][j] = e;
                sum += e;
            }
            #pragma unroll
            for (int msk = 1; msk < 16; msk <<= 1) sum += __shfl_xor(sum, msk);
            l[j] = sum;
        }
        // PV: 10 K-steps of 32 keys; P round-trips per-wave LDS (in-order DS)
        f32x4 oa0 = (f32x4){0.f,0.f,0.f,0.f}, oa1 = (f32x4){0.f,0.f,0.f,0.f};
        #pragma unroll
        for (int st = 0; st < 10; st++) {
            #pragma unroll
            for (int j = 0; j < 4; j++) {
                Pw[(fq*4 + j)*PB_ST + fr]      = f2bf(s[2*st][j]);
                Pw[(fq*4 + j)*PB_ST + 16 + fr] = (2*st + 1 < 19) ? f2bf(s[2*st+1][j])
                                                                 : (unsigned short)0;
            }
            const s16x8 ap = *(const s16x8*)&Pw[fr*PB_ST + fq*8];
            const s16x8 b0 = *(const s16x8*)&Vt[fr*VT_ST + st*32 + fq*8];
            const s16x8 b1 = *(const s16x8*)&Vt[(16 + fr)*VT_ST + st*32 + fq*8];
            oa0 = __builtin_amdgcn_mfma_f32_16x16x32_bf16(ap, b0, oa0, 0, 0, 0);
            oa1 = __builtin_amdgcn_mfma_f32_16x16x32_bf16(ap, b1, oa1, 0, 0, 0);
        }
        // store (bf16), rows fq*4+j, cols d = {fr, 16+fr}
        #pragma unroll
        for (int j = 0; j < 4; j++) {
            const int q = qt*16 + fq*4 + j;
            if (q < 300) {
                const float inv = 1.0f / l[j];
                unsigned short* op = o + ((size_t)(b*4800 + q*16 + p))*256 + h*32;
                op[fr]      = f2bf(oa0[j] * inv);
                op[16 + fr] = f2bf(oa1[j] * inv);
            }
        }
    }
}

// ---------------------------------------------------------------------------
// Fused add + LayerNorm over C=256. One block (256 thr) per row.
// ---------------------------------------------------------------------------
__global__ __launch_bounds__(256) void ln_add_kernel(
    const float* __restrict__ a, const float* __restrict__ b2,
    const float* __restrict__ g, const float* __restrict__ be,
    float* __restrict__ out)
{
    const int row = blockIdx.x;
    const int c = threadIdx.x;
    const size_t idx = (size_t)row * 256 + c;
    const float x = a[idx] + b2[idx];
    float s = x, s2 = x * x;
    #pragma unroll
    for (int m = 32; m >= 1; m >>= 1) {
        s  += __shfl_xor(s, m);
        s2 += __shfl_xor(s2, m);
    }
    __shared__ float ws1[4], ws2[4];
    const int w = threadIdx.x >> 6;
    if ((threadIdx.x & 63) == 0) { ws1[w] = s; ws2[w] = s2; }
    __syncthreads();
    s  = ws1[0] + ws1[1] + ws1[2] + ws1[3];
    s2 = ws2[0] + ws2[1] + ws2[2] + ws2[3];
    const float mean = s * (1.f/256.f);
    const float var  = s2 * (1.f/256.f) - mean * mean;
    const float r = rsqrtf(var + 1e-5f);
    out[idx] = (x - mean) * r * g[c] + be[c];
}

// ---------------------------------------------------------------------------
// MSDA sampling: value/samp now bf16 (halves gather + write traffic).
// ---------------------------------------------------------------------------
__global__ __launch_bounds__(256) void msda_kernel(
    const unsigned short* __restrict__ value, // (B*LIN, 256) bf16
    const float* __restrict__ offsattw,       // (B*4800, 384)
    const float* __restrict__ refp,           // (B*4800, 4, 2)
    unsigned short* __restrict__ samp)        // (B*4800, 256) bf16
{
    const int row = blockIdx.x;
    const int b = row / LQ;
    const int tid = threadIdx.x;
    const int h = tid >> 5, lane = tid & 31;

    const float* aw_p = offsattw + (size_t)row * 384 + 256 + h * 16;
    float lg[16];
    float mx = -1e30f;
    #pragma unroll
    for (int i = 0; i < 16; i++) { lg[i] = aw_p[i]; mx = fmaxf(mx, lg[i]); }
    float ssum = 0.f;
    #pragma unroll
    for (int i = 0; i < 16; i++) { lg[i] = __expf(lg[i] - mx); ssum += lg[i]; }
    const float rs = 1.0f / ssum;

    const float* ofs_p = offsattw + (size_t)row * 384 + h * 32;
    const float* ref_p = refp + (size_t)row * 8;
    const int Wl[4] = {128, 64, 32, 16};
    const int ST[4] = {0, 16384, 20480, 21504};
    float acc = 0.f;
    #pragma unroll
    for (int l = 0; l < 4; l++) {
        const float rx = ref_p[l*2 + 0];
        const float ry = ref_p[l*2 + 1];
        const int W = Wl[l], H = Wl[l];
        const float fW = (float)W, fH = (float)H;
        const unsigned short* vbase = value + ((size_t)b * LIN_TOT + ST[l]) * 256 + h * 32 + lane;
        #pragma unroll
        for (int pt = 0; pt < 4; pt++) {
            const float ox = ofs_p[(l*4 + pt)*2 + 0];
            const float oy = ofs_p[(l*4 + pt)*2 + 1];
            const float x = (rx + ox / fW) * fW - 0.5f;
            const float y = (ry + oy / fH) * fH - 0.5f;
            const float x0 = floorf(x), y0 = floorf(y);
            const float wx = x - x0, wy = y - y0;
            const int x0i = (int)x0, y0i = (int)y0;
            float v[4];
            #pragma unroll
            for (int cr = 0; cr < 4; cr++) {
                const int xi = x0i + (cr & 1);
                const int yi = y0i + (cr >> 1);
                const bool valid = (xi >= 0) & (xi < W) & (yi >= 0) & (yi < H);
                const int xc = min(max(xi, 0), W - 1);
                const int yc = min(max(yi, 0), H - 1);
                const float gv = bf2f(vbase[(size_t)(yc * W + xc) * 256]);
                v[cr] = valid ? gv : 0.f;
            }
            const float sv = (1.f-wx)*(1.f-wy)*v[0] + wx*(1.f-wy)*v[1]
                           + (1.f-wx)*wy*v[2]       + wx*wy*v[3];
            acc += lg[l*4 + pt] * rs * sv;
        }
    }
    samp[(size_t)row * 256 + h * 32 + lane] = f2bf(acc);
}

// ---------------------------------------------------------------------------
// Workspace layout (floats), lifetime reuse (same 197.3 MB footprint).
//   A [0, 22282240):        qkv(bf16) -> value(bf16) -> hbuf(bf16)
//   B [22282240,+4915200):  o1(bf16) -> samp(bf16) -> f2(fp32)
//   C [27197440,+4915200):  o2 -> t2
//   D [32112640,+4915200):  x1
//   E [37027840,+7372800):  offsattw (19200 x 384)
//   F [44400640,+4915200):  Wmerged+bias (head, dead early) -> x2 (late)
// ---------------------------------------------------------------------------
extern "C" void kernel_launch(void* const* d_in, const int* in_sizes, int n_in,
                              void* d_out, int out_size, void* d_ws, size_t ws_size,
                              hipStream_t stream)
{
    const float* tgt        = (const float*)d_in[0];
    const float* query_pos  = (const float*)d_in[1];
    const float* refp       = (const float*)d_in[2];
    const float* src        = (const float*)d_in[3];
    const float* inproj_w   = (const float*)d_in[6];
    const float* inproj_b   = (const float*)d_in[7];
    const float* outproj_w  = (const float*)d_in[8];
    const float* outproj_b  = (const float*)d_in[9];
    const float* ln_inter_g = (const float*)d_in[10];
    const float* ln_inter_b = (const float*)d_in[11];
    const float* ln_cross_g = (const float*)d_in[12];
    const float* ln_cross_b = (const float*)d_in[13];
    const float* ln3_g      = (const float*)d_in[14];
    const float* ln3_b      = (const float*)d_in[15];
    const float* off_w      = (const float*)d_in[16];
    const float* off_b      = (const float*)d_in[17];
    const float* attw_w     = (const float*)d_in[18];
    const float* attw_b     = (const float*)d_in[19];
    const float* val_w      = (const float*)d_in[20];
    const float* val_b      = (const float*)d_in[21];
    const float* mout_w     = (const float*)d_in[22];
    const float* mout_b     = (const float*)d_in[23];
    const float* lin1_w     = (const float*)d_in[24];
    const float* lin1_b     = (const float*)d_in[25];
    const float* lin2_w     = (const float*)d_in[26];
    const float* lin2_b     = (const float*)d_in[27];

    float* ws = (float*)d_ws;
    unsigned short* qkv   = (unsigned short*)ws;           // A (bf16)
    unsigned short* value = (unsigned short*)ws;           // A (bf16)
    unsigned short* hbuf  = (unsigned short*)ws;           // A (bf16)
    unsigned short* o1    = (unsigned short*)(ws + 22282240); // B (bf16)
    unsigned short* samp  = o1;                            // B (bf16)
    float* f2      = ws + 22282240;                        // B (fp32)
    float* o2      = ws + 27197440;                        // C
    float* t2      = o2;
    float* x1      = ws + 32112640;                        // D
    float* offsattw= ws + 37027840;                        // E
    float* Wm      = ws + 44400640;                        // F head
    float* Wb      = Wm + 98304;
    float* x2      = ws + 44400640;                        // F
    float* outp    = (float*)d_out;

    // 0) pack merged offs|attw weights + biases
    hipMemcpyAsync(Wm,          off_w,  65536u * 4, hipMemcpyDeviceToDevice, stream);
    hipMemcpyAsync(Wm + 65536,  attw_w, 32768u * 4, hipMemcpyDeviceToDevice, stream);
    hipMemcpyAsync(Wb,          off_b,  256u * 4,   hipMemcpyDeviceToDevice, stream);
    hipMemcpyAsync(Wb + 256,    attw_b, 128u * 4,   hipMemcpyDeviceToDevice, stream);

    // 1) qkv = tgt @ inproj^T + b  -> bf16
    gemm_mfma<0,1,0,0><<<dim3(12,150), 256, 0, stream>>>(tgt, nullptr, inproj_w, inproj_b, qkv, NROW, 768, 256);
    // 2) self-attention (MFMA) -> bf16 o1
    attn_mfma<<<512, 256, 0, stream>>>(qkv, o1);
    // 3) outproj (A bf16)
    gemm_mfma<0,0,1,0><<<dim3(4,150), 256, 0, stream>>>(o1, nullptr, outproj_w, outproj_b, o2, NROW, 256, 256);
    // 4) x1 = LN(tgt + o2)
    ln_add_kernel<<<NROW, 256, 0, stream>>>(tgt, o2, ln_inter_g, ln_inter_b, x1);
    // 5) offs|attw = (x1 + query_pos) @ Wm^T + Wb
    gemm_mfma<0,0,0,1><<<dim3(6,150), 256, 0, stream>>>(x1, query_pos, Wm, Wb, offsattw, NROW, 384, 256);
    // 6) value projection -> bf16
    gemm_mfma<0,1,0,0><<<dim3(4,680), 256, 0, stream>>>(src, nullptr, val_w, val_b, value, B_DIM * LIN_TOT, 256, 256);
    // 7) deformable sampling (bf16 value, bf16 samp)
    msda_kernel<<<NROW, 256, 0, stream>>>(value, offsattw, refp, samp);
    // 8) mout (A bf16)
    gemm_mfma<0,0,1,0><<<dim3(4,150), 256, 0, stream>>>(samp, nullptr, mout_w, mout_b, t2, NROW, 256, 256);
    // 9) x2 = LN(x1 + t2)
    ln_add_kernel<<<NROW, 256, 0, stream>>>(x1, t2, ln_cross_g, ln_cross_b, x2);
    // 10) FFN up + ReLU -> bf16
    gemm_mfma<1,1,0,0><<<dim3(16,150), 256, 0, stream>>>(x2, nullptr, lin1_w, lin1_b, hbuf, NROW, DFF, 256);
    // 11) FFN down (A bf16)
    gemm_mfma<0,0,1,0><<<dim3(4,150), 256, 0, stream>>>(hbuf, nullptr, lin2_w, lin2_b, f2, NROW, 256, DFF);
    // 12) out = LN(x2 + f2)
    ln_add_kernel<<<NROW, 256, 0, stream>>>(x2, f2, ln3_g, ln3_b, outp);
}

// Round 8
// 632.738 us; speedup vs baseline: 2.5108x; 1.0644x over previous
//
#include <hip/hip_runtime.h>
#include <cstdint>
#include <cstddef>

#define B_DIM 4
#define Q_DIM 300
#define P_DIM 16
#define C_DIM 256
#define NHD 8
#define DH 32
#define LQ (Q_DIM*P_DIM)      /* 4800 */
#define NROW (B_DIM*LQ)       /* 19200 */
#define LIN_TOT 21760
#define DFF 1024

typedef __attribute__((ext_vector_type(8))) short s16x8;   // 8 x bf16 (4 VGPR)
typedef __attribute__((ext_vector_type(4))) float f32x4;   // MFMA C/D frag

__device__ __forceinline__ unsigned short f2bf(float f) {
    unsigned u = __float_as_uint(f);
    u = u + 0x7FFFu + ((u >> 16) & 1u);   // round-to-nearest-even
    return (unsigned short)(u >> 16);
}
__device__ __forceinline__ float bf2f(unsigned short s) {
    return __uint_as_float(((unsigned)s) << 16);
}

// ---------------------------------------------------------------------------
// bf16 MFMA NT GEMM (unchanged, verified rounds 3/5).
// ---------------------------------------------------------------------------
template<int RELU, int OBF16, int ABF16, int ADDA>
__global__ __launch_bounds__(256) void gemm_mfma(
    const void* __restrict__ Av, const float* __restrict__ A2,
    const float* __restrict__ W, const float* __restrict__ bias,
    void* __restrict__ Cv, int M, int N, int K)
{
    __shared__ unsigned short As[128 * 72];
    __shared__ unsigned short Ws[64 * 72];
    const int tid = threadIdx.x;
    const int bm = blockIdx.y * 128;
    const int bn = blockIdx.x * 64;
    const int ar = tid >> 1;
    const int ac = (tid & 1) * 32;
    const int wr = tid >> 2;
    const int wc = (tid & 3) * 16;
    const float* Af = (const float*)Av;
    const unsigned short* Ab = (const unsigned short*)Av;
    const float* Afp = Af + (size_t)(bm + ar) * K + ac;
    const unsigned short* Abp = Ab + (size_t)(bm + ar) * K + ac;
    const float* A2p = A2 ? (A2 + (size_t)(bm + ar) * K + ac) : nullptr;
    const float* Wp  = W + (size_t)(bn + wr) * K + wc;
    const int lane = tid & 63;
    const int wid  = tid >> 6;
    const int wm = wid >> 1, wn = wid & 1;
    const int fr = lane & 15;
    const int fq = lane >> 4;
    f32x4 acc[4][2];
    #pragma unroll
    for (int m = 0; m < 4; m++)
        #pragma unroll
        for (int n = 0; n < 2; n++)
            acc[m][n] = (f32x4){0.f, 0.f, 0.f, 0.f};

    for (int k0 = 0; k0 < K; k0 += 64) {
        __syncthreads();
        if (ABF16) {
            #pragma unroll
            for (int j = 0; j < 4; j++)
                *(uint4*)&As[ar*72 + ac + j*8] = *(const uint4*)(Abp + k0 + j*8);
        } else {
            #pragma unroll
            for (int j = 0; j < 4; j++) {
                float4 x = *(const float4*)(Afp + k0 + j*8);
                float4 y = *(const float4*)(Afp + k0 + j*8 + 4);
                if (ADDA) {
                    float4 u = *(const float4*)(A2p + k0 + j*8);
                    float4 v = *(const float4*)(A2p + k0 + j*8 + 4);
                    x.x += u.x; x.y += u.y; x.z += u.z; x.w += u.w;
                    y.x += v.x; y.y += v.y; y.z += v.z; y.w += v.w;
                }
                union { unsigned short s[8]; uint4 v; } pk;
                pk.s[0]=f2bf(x.x); pk.s[1]=f2bf(x.y); pk.s[2]=f2bf(x.z); pk.s[3]=f2bf(x.w);
                pk.s[4]=f2bf(y.x); pk.s[5]=f2bf(y.y); pk.s[6]=f2bf(y.z); pk.s[7]=f2bf(y.w);
                *(uint4*)&As[ar*72 + ac + j*8] = pk.v;
            }
        }
        #pragma unroll
        for (int j = 0; j < 2; j++) {
            float4 x = *(const float4*)(Wp + k0 + j*8);
            float4 y = *(const float4*)(Wp + k0 + j*8 + 4);
            union { unsigned short s[8]; uint4 v; } pk;
            pk.s[0]=f2bf(x.x); pk.s[1]=f2bf(x.y); pk.s[2]=f2bf(x.z); pk.s[3]=f2bf(x.w);
            pk.s[4]=f2bf(y.x); pk.s[5]=f2bf(y.y); pk.s[6]=f2bf(y.z); pk.s[7]=f2bf(y.w);
            *(uint4*)&Ws[wr*72 + wc + j*8] = pk.v;
        }
        __syncthreads();
        #pragma unroll
        for (int ks = 0; ks < 64; ks += 32) {
            s16x8 a0 = *(const s16x8*)&As[(wm*64 +  0 + fr)*72 + ks + fq*8];
            s16x8 a1 = *(const s16x8*)&As[(wm*64 + 16 + fr)*72 + ks + fq*8];
            s16x8 a2 = *(const s16x8*)&As[(wm*64 + 32 + fr)*72 + ks + fq*8];
            s16x8 a3 = *(const s16x8*)&As[(wm*64 + 48 + fr)*72 + ks + fq*8];
            s16x8 b0 = *(const s16x8*)&Ws[(wn*32 +  0 + fr)*72 + ks + fq*8];
            s16x8 b1 = *(const s16x8*)&Ws[(wn*32 + 16 + fr)*72 + ks + fq*8];
            acc[0][0] = __builtin_amdgcn_mfma_f32_16x16x32_bf16(a0, b0, acc[0][0], 0, 0, 0);
            acc[0][1] = __builtin_amdgcn_mfma_f32_16x16x32_bf16(a0, b1, acc[0][1], 0, 0, 0);
            acc[1][0] = __builtin_amdgcn_mfma_f32_16x16x32_bf16(a1, b0, acc[1][0], 0, 0, 0);
            acc[1][1] = __builtin_amdgcn_mfma_f32_16x16x32_bf16(a1, b1, acc[1][1], 0, 0, 0);
            acc[2][0] = __builtin_amdgcn_mfma_f32_16x16x32_bf16(a2, b0, acc[2][0], 0, 0, 0);
            acc[2][1] = __builtin_amdgcn_mfma_f32_16x16x32_bf16(a2, b1, acc[2][1], 0, 0, 0);
            acc[3][0] = __builtin_amdgcn_mfma_f32_16x16x32_bf16(a3, b0, acc[3][0], 0, 0, 0);
            acc[3][1] = __builtin_amdgcn_mfma_f32_16x16x32_bf16(a3, b1, acc[3][1], 0, 0, 0);
        }
    }
    float* Co = (float*)Cv;
    unsigned short* Cb = (unsigned short*)Cv;
    #pragma unroll
    for (int m = 0; m < 4; m++) {
        const int r0 = bm + wm*64 + m*16 + fq*4;
        #pragma unroll
        for (int n = 0; n < 2; n++) {
            const int col = bn + wn*32 + n*16 + fr;
            const float bsv = bias[col];
            #pragma unroll
            for (int j = 0; j < 4; j++) {
                float v = acc[m][n][j] + bsv;
                if (RELU) v = fmaxf(v, 0.f);
                if (OBF16) Cb[(size_t)(r0 + j) * N + col] = f2bf(v);
                else       Co[(size_t)(r0 + j) * N + col] = v;
            }
        }
    }
}

// ---------------------------------------------------------------------------
// MFMA self-attention (unchanged, verified round 5).
// ---------------------------------------------------------------------------
#define KS_ST 40
#define VT_ST 328
#define PB_ST 40
__global__ __launch_bounds__(256) void attn_mfma(
    const unsigned short* __restrict__ qkv, unsigned short* __restrict__ o)
{
    const int h  = blockIdx.x & 7;
    const int bp = blockIdx.x >> 3;   // b*16+p
    const int p  = bp & 15;
    const int b  = bp >> 4;
    __shared__ unsigned short Ks[304 * KS_ST];
    __shared__ unsigned short Vt[32 * VT_ST];
    __shared__ unsigned short Pb[4][16 * PB_ST];
    const int tid = threadIdx.x;
    const size_t qbase = ((size_t)b * 4800 + p) * 768 + h * 32; // + q*16*768
    for (int k = tid; k < 304; k += 256) {
        uint4 v0, v1, v2, v3;
        if (k < 300) {
            const unsigned short* src = qkv + qbase + (size_t)k * (16*768) + 256;
            v0 = *(const uint4*)(src);      v1 = *(const uint4*)(src + 8);
            v2 = *(const uint4*)(src + 16); v3 = *(const uint4*)(src + 24);
        } else {
            v0 = v1 = v2 = v3 = make_uint4(0u, 0u, 0u, 0u);
        }
        *(uint4*)&Ks[k*KS_ST +  0] = v0; *(uint4*)&Ks[k*KS_ST +  8] = v1;
        *(uint4*)&Ks[k*KS_ST + 16] = v2; *(uint4*)&Ks[k*KS_ST + 24] = v3;
    }
    for (int k = tid; k < 320; k += 256) {
        union { uint4 v[4]; unsigned short s[32]; } t;
        if (k < 300) {
            const unsigned short* src = qkv + qbase + (size_t)k * (16*768) + 512;
            t.v[0] = *(const uint4*)(src);      t.v[1] = *(const uint4*)(src + 8);
            t.v[2] = *(const uint4*)(src + 16); t.v[3] = *(const uint4*)(src + 24);
        } else {
            t.v[0] = t.v[1] = t.v[2] = t.v[3] = make_uint4(0u, 0u, 0u, 0u);
        }
        #pragma unroll
        for (int d = 0; d < 32; d++) Vt[d*VT_ST + k] = t.s[d];
    }
    __syncthreads();

    const int wid = tid >> 6, lane = tid & 63;
    const int fr = lane & 15, fq = lane >> 4;
    const float scale = 0.17677669529663689f; // 1/sqrt(32)
    unsigned short* Pw = &Pb[wid][0];

    for (int qt = wid; qt < 19; qt += 4) {
        int qr = qt*16 + fr; if (qr > 299) qr = 299;
        const s16x8 aq = *(const s16x8*)(qkv + qbase + (size_t)qr * (16*768) + fq*8);
        f32x4 s[19];
        #pragma unroll
        for (int t = 0; t < 19; t++) {
            s16x8 bk = *(const s16x8*)&Ks[(t*16 + fr)*KS_ST + fq*8];
            s[t] = __builtin_amdgcn_mfma_f32_16x16x32_bf16(aq, bk, (f32x4){0.f,0.f,0.f,0.f}, 0, 0, 0);
        }
        if (fr >= 12) s[18] = (f32x4){-1e30f, -1e30f, -1e30f, -1e30f}; // keys >= 300
        float mx[4], l[4];
        #pragma unroll
        for (int j = 0; j < 4; j++) {
            float m = s[0][j];
            #pragma unroll
            for (int t = 1; t < 19; t++) m = fmaxf(m, s[t][j]);
            #pragma unroll
            for (int msk = 1; msk < 16; msk <<= 1) m = fmaxf(m, __shfl_xor(m, msk));
            mx[j] = m;
        }
        #pragma unroll
        for (int j = 0; j < 4; j++) {
            float sum = 0.f;
            #pragma unroll
            for (int t = 0; t < 19; t++) {
                const float e = __expf((s[t][j] - mx[j]) * scale);
                s[t][j] = e;
                sum += e;
            }
            #pragma unroll
            for (int msk = 1; msk < 16; msk <<= 1) sum += __shfl_xor(sum, msk);
            l[j] = sum;
        }
        f32x4 oa0 = (f32x4){0.f,0.f,0.f,0.f}, oa1 = (f32x4){0.f,0.f,0.f,0.f};
        #pragma unroll
        for (int st = 0; st < 10; st++) {
            #pragma unroll
            for (int j = 0; j < 4; j++) {
                Pw[(fq*4 + j)*PB_ST + fr]      = f2bf(s[2*st][j]);
                Pw[(fq*4 + j)*PB_ST + 16 + fr] = (2*st + 1 < 19) ? f2bf(s[2*st+1][j])
                                                                 : (unsigned short)0;
            }
            const s16x8 ap = *(const s16x8*)&Pw[fr*PB_ST + fq*8];
            const s16x8 b0 = *(const s16x8*)&Vt[fr*VT_ST + st*32 + fq*8];
            const s16x8 b1 = *(const s16x8*)&Vt[(16 + fr)*VT_ST + st*32 + fq*8];
            oa0 = __builtin_amdgcn_mfma_f32_16x16x32_bf16(ap, b0, oa0, 0, 0, 0);
            oa1 = __builtin_amdgcn_mfma_f32_16x16x32_bf16(ap, b1, oa1, 0, 0, 0);
        }
        #pragma unroll
        for (int j = 0; j < 4; j++) {
            const int q = qt*16 + fq*4 + j;
            if (q < 300) {
                const float inv = 1.0f / l[j];
                unsigned short* op = o + ((size_t)(b*4800 + q*16 + p))*256 + h*32;
                op[fr]      = f2bf(oa0[j] * inv);
                op[16 + fr] = f2bf(oa1[j] * inv);
            }
        }
    }
}

// ---------------------------------------------------------------------------
// Fused add + LayerNorm over C=256. One block (256 thr) per row.
// ---------------------------------------------------------------------------
__global__ __launch_bounds__(256) void ln_add_kernel(
    const float* __restrict__ a, const float* __restrict__ b2,
    const float* __restrict__ g, const float* __restrict__ be,
    float* __restrict__ out)
{
    const int row = blockIdx.x;
    const int c = threadIdx.x;
    const size_t idx = (size_t)row * 256 + c;
    const float x = a[idx] + b2[idx];
    float s = x, s2 = x * x;
    #pragma unroll
    for (int m = 32; m >= 1; m >>= 1) {
        s  += __shfl_xor(s, m);
        s2 += __shfl_xor(s2, m);
    }
    __shared__ float ws1[4], ws2[4];
    const int w = threadIdx.x >> 6;
    if ((threadIdx.x & 63) == 0) { ws1[w] = s; ws2[w] = s2; }
    __syncthreads();
    s  = ws1[0] + ws1[1] + ws1[2] + ws1[3];
    s2 = ws2[0] + ws2[1] + ws2[2] + ws2[3];
    const float mean = s * (1.f/256.f);
    const float var  = s2 * (1.f/256.f) - mean * mean;
    const float r = rsqrtf(var + 1e-5f);
    out[idx] = (x - mean) * r * g[c] + be[c];
}

// ---------------------------------------------------------------------------
// MSDA sampling, wave-per-(row,head), task-parallel.
// Phase 1: lane l owns task (point l>>2, corner l&3): softmax weight (stride-4
//          shfl_xor tree), position math, clamp/valid, byte offset + weight.
//          Zero cross-lane redundancy (was 32x redundant).
// Phase 2: 4 iters; lane serves task g*16+(l>>2) at channel-quarter (l&3),
//          address+weight via __shfl, loads uint4 (8 bf16 = 16B).
// Phase 3: stride-4 shfl_xor reduce of acc[8]; lanes 0..3 store 16B each.
// ---------------------------------------------------------------------------
__global__ __launch_bounds__(256) void msda_kernel(
    const unsigned short* __restrict__ value,  // (B*LIN, 256) bf16
    const float* __restrict__ offsattw,        // (B*4800, 384) fp32
    const float* __restrict__ refp,            // (B*4800, 4, 2) fp32
    unsigned short* __restrict__ samp)         // (B*4800, 256) bf16
{
    const int task = blockIdx.x * 4 + (threadIdx.x >> 6);  // (row, h)
    const int row = task >> 3;
    const int h   = task & 7;
    const int l   = threadIdx.x & 63;
    const int s   = l >> 2;      // phase1: point / phase2: task slot
    const int cq  = l & 3;       // phase1: corner / phase2: channel quarter

    const float* base = offsattw + (size_t)row * 384;
    // ---- softmax weight for point s (16 distinct points on stride-4 lanes) --
    const float lg = base[256 + h*16 + s];
    float mxv = lg;
    #pragma unroll
    for (int m = 4; m < 64; m <<= 1) mxv = fmaxf(mxv, __shfl_xor(mxv, m));
    const float e = __expf(lg - mxv);
    float ssum = e;
    #pragma unroll
    for (int m = 4; m < 64; m <<= 1) ssum += __shfl_xor(ssum, m);
    const float w_att = e * (1.0f / ssum);
    // ---- bilinear geometry for (point s, corner cq) ----
    const int lv = s >> 2;
    const int Wtab[4]  = {128, 64, 32, 16};
    const int STtab[4] = {0, 16384, 20480, 21504};
    const int W = Wtab[lv];
    const float fW = (float)W;
    const float ox = base[h*32 + s*2];
    const float oy = base[h*32 + s*2 + 1];
    const float rx = refp[(size_t)row*8 + lv*2];
    const float ry = refp[(size_t)row*8 + lv*2 + 1];
    const float x = (rx + ox / fW) * fW - 0.5f;
    const float y = (ry + oy / fW) * fW - 0.5f;
    const float x0f = floorf(x), y0f = floorf(y);
    const float wx = x - x0f, wy = y - y0f;
    const int xi = (int)x0f + (cq & 1);
    const int yi = (int)y0f + (cq >> 1);
    const bool valid = (xi >= 0) & (xi < W) & (yi >= 0) & (yi < W);
    const int xc = min(max(xi, 0), W - 1);
    const int yc = min(max(yi, 0), W - 1);
    const float wxs = (cq & 1)  ? wx : 1.f - wx;
    const float wys = (cq >> 1) ? wy : 1.f - wy;
    const float wgt = valid ? (w_att * wxs * wys) : 0.f;
    const unsigned boff = (unsigned)(STtab[lv] + yc * W + xc) * 512u + (unsigned)h * 64u;

    const char* vb = (const char*)(value + (size_t)(row / LQ) * LIN_TOT * 256);
    float acc[8] = {0.f, 0.f, 0.f, 0.f, 0.f, 0.f, 0.f, 0.f};
    #pragma unroll
    for (int g = 0; g < 4; g++) {
        const int src = g * 16 + s;
        const unsigned a = (unsigned)__shfl((int)boff, src);
        const float    w = __shfl(wgt, src);
        const uint4 v4 = *(const uint4*)(vb + a + cq * 16);
        const unsigned u[4] = {v4.x, v4.y, v4.z, v4.w};
        #pragma unroll
        for (int j = 0; j < 4; j++) {
            acc[2*j]   += w * __uint_as_float(u[j] << 16);
            acc[2*j+1] += w * __uint_as_float(u[j] & 0xFFFF0000u);
        }
    }
    // ---- reduce over the 16 task slots ----
    #pragma unroll
    for (int m = 4; m < 64; m <<= 1)
        #pragma unroll
        for (int j = 0; j < 8; j++)
            acc[j] += __shfl_xor(acc[j], m);
    if (s == 0) {
        union { unsigned short sh[8]; uint4 v; } pk;
        #pragma unroll
        for (int j = 0; j < 8; j++) pk.sh[j] = f2bf(acc[j]);
        *(uint4*)(samp + (size_t)row * 256 + h * 32 + cq * 8) = pk.v;
    }
}

// ---------------------------------------------------------------------------
// Workspace layout (floats), lifetime reuse (same 197.3 MB footprint).
//   A [0, 22282240):        qkv(bf16) -> value(bf16) -> hbuf(bf16)
//   B [22282240,+4915200):  o1(bf16) -> samp(bf16) -> f2(fp32)
//   C [27197440,+4915200):  o2 -> t2
//   D [32112640,+4915200):  x1
//   E [37027840,+7372800):  offsattw (19200 x 384)
//   F [44400640,+4915200):  Wmerged+bias (head, dead early) -> x2 (late)
// ---------------------------------------------------------------------------
extern "C" void kernel_launch(void* const* d_in, const int* in_sizes, int n_in,
                              void* d_out, int out_size, void* d_ws, size_t ws_size,
                              hipStream_t stream)
{
    const float* tgt        = (const float*)d_in[0];
    const float* query_pos  = (const float*)d_in[1];
    const float* refp       = (const float*)d_in[2];
    const float* src        = (const float*)d_in[3];
    const float* inproj_w   = (const float*)d_in[6];
    const float* inproj_b   = (const float*)d_in[7];
    const float* outproj_w  = (const float*)d_in[8];
    const float* outproj_b  = (const float*)d_in[9];
    const float* ln_inter_g = (const float*)d_in[10];
    const float* ln_inter_b = (const float*)d_in[11];
    const float* ln_cross_g = (const float*)d_in[12];
    const float* ln_cross_b = (const float*)d_in[13];
    const float* ln3_g      = (const float*)d_in[14];
    const float* ln3_b      = (const float*)d_in[15];
    const float* off_w      = (const float*)d_in[16];
    const float* off_b      = (const float*)d_in[17];
    const float* attw_w     = (const float*)d_in[18];
    const float* attw_b     = (const float*)d_in[19];
    const float* val_w      = (const float*)d_in[20];
    const float* val_b      = (const float*)d_in[21];
    const float* mout_w     = (const float*)d_in[22];
    const float* mout_b     = (const float*)d_in[23];
    const float* lin1_w     = (const float*)d_in[24];
    const float* lin1_b     = (const float*)d_in[25];
    const float* lin2_w     = (const float*)d_in[26];
    const float* lin2_b     = (const float*)d_in[27];

    float* ws = (float*)d_ws;
    unsigned short* qkv   = (unsigned short*)ws;           // A (bf16)
    unsigned short* value = (unsigned short*)ws;           // A (bf16)
    unsigned short* hbuf  = (unsigned short*)ws;           // A (bf16)
    unsigned short* o1    = (unsigned short*)(ws + 22282240); // B (bf16)
    unsigned short* samp  = o1;                            // B (bf16)
    float* f2      = ws + 22282240;                        // B (fp32)
    float* o2      = ws + 27197440;                        // C
    float* t2      = o2;
    float* x1      = ws + 32112640;                        // D
    float* offsattw= ws + 37027840;                        // E
    float* Wm      = ws + 44400640;                        // F head
    float* Wb      = Wm + 98304;
    float* x2      = ws + 44400640;                        // F
    float* outp    = (float*)d_out;

    // 0) pack merged offs|attw weights + biases
    hipMemcpyAsync(Wm,          off_w,  65536u * 4, hipMemcpyDeviceToDevice, stream);
    hipMemcpyAsync(Wm + 65536,  attw_w, 32768u * 4, hipMemcpyDeviceToDevice, stream);
    hipMemcpyAsync(Wb,          off_b,  256u * 4,   hipMemcpyDeviceToDevice, stream);
    hipMemcpyAsync(Wb + 256,    attw_b, 128u * 4,   hipMemcpyDeviceToDevice, stream);

    // 1) qkv = tgt @ inproj^T + b  -> bf16
    gemm_mfma<0,1,0,0><<<dim3(12,150), 256, 0, stream>>>(tgt, nullptr, inproj_w, inproj_b, qkv, NROW, 768, 256);
    // 2) self-attention (MFMA) -> bf16 o1
    attn_mfma<<<512, 256, 0, stream>>>(qkv, o1);
    // 3) outproj (A bf16)
    gemm_mfma<0,0,1,0><<<dim3(4,150), 256, 0, stream>>>(o1, nullptr, outproj_w, outproj_b, o2, NROW, 256, 256);
    // 4) x1 = LN(tgt + o2)
    ln_add_kernel<<<NROW, 256, 0, stream>>>(tgt, o2, ln_inter_g, ln_inter_b, x1);
    // 5) offs|attw = (x1 + query_pos) @ Wm^T + Wb
    gemm_mfma<0,0,0,1><<<dim3(6,150), 256, 0, stream>>>(x1, query_pos, Wm, Wb, offsattw, NROW, 384, 256);
    // 6) value projection -> bf16
    gemm_mfma<0,1,0,0><<<dim3(4,680), 256, 0, stream>>>(src, nullptr, val_w, val_b, value, B_DIM * LIN_TOT, 256, 256);
    // 7) deformable sampling (wave per (row,head))
    msda_kernel<<<38400, 256, 0, stream>>>(value, offsattw, refp, samp);
    // 8) mout (A bf16)
    gemm_mfma<0,0,1,0><<<dim3(4,150), 256, 0, stream>>>(samp, nullptr, mout_w, mout_b, t2, NROW, 256, 256);
    // 9) x2 = LN(x1 + t2)
    ln_add_kernel<<<NROW, 256, 0, stream>>>(x1, t2, ln_cross_g, ln_cross_b, x2);
    // 10) FFN up + ReLU -> bf16
    gemm_mfma<1,1,0,0><<<dim3(16,150), 256, 0, stream>>>(x2, nullptr, lin1_w, lin1_b, hbuf, NROW, DFF, 256);
    // 11) FFN down (A bf16)
    gemm_mfma<0,0,1,0><<<dim3(4,150), 256, 0, stream>>>(hbuf, nullptr, lin2_w, lin2_b, f2, NROW, 256, DFF);
    // 12) out = LN(x2 + f2)
    ln_add_kernel<<<NROW, 256, 0, stream>>>(x2, f2, ln3_g, ln3_b, outp);
}

// Round 12
// 517.063 us; speedup vs baseline: 3.0725x; 1.2237x over previous
//
#include <hip/hip_runtime.h>
#include <cstdint>
#include <cstddef>

#define B_DIM 4
#define Q_DIM 300
#define P_DIM 16
#define C_DIM 256
#define NHD 8
#define DH 32
#define LQ (Q_DIM*P_DIM)      /* 4800 */
#define NROW (B_DIM*LQ)       /* 19200 */
#define LIN_TOT 21760
#define DFF 1024

typedef __attribute__((ext_vector_type(8))) short s16x8;   // 8 x bf16 (4 VGPR)
typedef __attribute__((ext_vector_type(4))) float f32x4;   // MFMA C/D frag

__device__ __forceinline__ unsigned short f2bf(float f) {
    unsigned u = __float_as_uint(f);
    u = u + 0x7FFFu + ((u >> 16) & 1u);   // round-to-nearest-even
    return (unsigned short)(u >> 16);
}

// ---------------------------------------------------------------------------
// fp32 -> bf16 cast, 8 elems/thread. n8 = n/8 (all sizes are multiples of 8).
// ---------------------------------------------------------------------------
__global__ __launch_bounds__(256) void cast_bf16(
    const float* __restrict__ s, unsigned short* __restrict__ d, int n8)
{
    const int i = blockIdx.x * 256 + threadIdx.x;
    if (i < n8) {
        const float4 x = *(const float4*)(s + (size_t)i*8);
        const float4 y = *(const float4*)(s + (size_t)i*8 + 4);
        union { unsigned short sh[8]; uint4 v; } pk;
        pk.sh[0]=f2bf(x.x); pk.sh[1]=f2bf(x.y); pk.sh[2]=f2bf(x.z); pk.sh[3]=f2bf(x.w);
        pk.sh[4]=f2bf(y.x); pk.sh[5]=f2bf(y.y); pk.sh[6]=f2bf(y.z); pk.sh[7]=f2bf(y.w);
        *(uint4*)(d + (size_t)i*8) = pk.v;
    }
}

// Batched weight cast: 8 tensors in one launch (blockIdx.y = tensor slot).
struct W8   { const float* s; unsigned short* d; int n8; };
struct W8x8 { W8 w[8]; };
__global__ __launch_bounds__(256) void cast_w8(W8x8 p)
{
    const W8 w = p.w[blockIdx.y];
    for (int i = blockIdx.x * 256 + threadIdx.x; i < w.n8; i += gridDim.x * 256) {
        const float4 x = *(const float4*)(w.s + (size_t)i*8);
        const float4 y = *(const float4*)(w.s + (size_t)i*8 + 4);
        union { unsigned short sh[8]; uint4 v; } pk;
        pk.sh[0]=f2bf(x.x); pk.sh[1]=f2bf(x.y); pk.sh[2]=f2bf(x.z); pk.sh[3]=f2bf(x.w);
        pk.sh[4]=f2bf(y.x); pk.sh[5]=f2bf(y.y); pk.sh[6]=f2bf(y.z); pk.sh[7]=f2bf(y.w);
        *(uint4*)(w.d + (size_t)i*8) = pk.v;
    }
}

// ---------------------------------------------------------------------------
// bf16 MFMA NT GEMM, BM=128 BN=128 BK=64; 4 waves 2x2, each 64x64 out (4x4
// frags). AFP32: A is fp32 in HBM, converted to bf16 during staging (the
// round-8-verified pattern); else A is bf16 and staging is pure 16B copies.
// ---------------------------------------------------------------------------
template<int RELU, int OBF16, int AFP32>
__global__ __launch_bounds__(256) void gemm_bf16_128(
    const void* __restrict__ Av, const unsigned short* __restrict__ W,
    const float* __restrict__ bias, void* __restrict__ Cv, int M, int N, int K)
{
    __shared__ unsigned short As[128 * 72];
    __shared__ unsigned short Ws[128 * 72];
    const int tid = threadIdx.x;
    const int bm = blockIdx.y * 128;
    const int bn = blockIdx.x * 128;
    const int r  = tid >> 1;             // 0..127 staging row (A and W)
    const int c  = (tid & 1) * 32;       // col half (elements)
    const unsigned short* Ab = (const unsigned short*)Av + (size_t)(bm + r) * K + c;
    const float*          Af = (const float*)Av          + (size_t)(bm + r) * K + c;
    const unsigned short* Wp = W + (size_t)(bn + r) * K + c;
    const int lane = tid & 63;
    const int wid  = tid >> 6;
    const int wm = wid >> 1, wn = wid & 1;
    const int fr = lane & 15;
    const int fq = lane >> 4;
    f32x4 acc[4][4];
    #pragma unroll
    for (int m = 0; m < 4; m++)
        #pragma unroll
        for (int n = 0; n < 4; n++)
            acc[m][n] = (f32x4){0.f, 0.f, 0.f, 0.f};

    for (int k0 = 0; k0 < K; k0 += 64) {
        __syncthreads();
        if (AFP32) {
            #pragma unroll
            for (int j = 0; j < 4; j++) {
                const float4 x = *(const float4*)(Af + k0 + j*8);
                const float4 y = *(const float4*)(Af + k0 + j*8 + 4);
                union { unsigned short sh[8]; uint4 v; } pk;
                pk.sh[0]=f2bf(x.x); pk.sh[1]=f2bf(x.y); pk.sh[2]=f2bf(x.z); pk.sh[3]=f2bf(x.w);
                pk.sh[4]=f2bf(y.x); pk.sh[5]=f2bf(y.y); pk.sh[6]=f2bf(y.z); pk.sh[7]=f2bf(y.w);
                *(uint4*)&As[r*72 + c + j*8] = pk.v;
                *(uint4*)&Ws[r*72 + c + j*8] = *(const uint4*)(Wp + k0 + j*8);
            }
        } else {
            #pragma unroll
            for (int j = 0; j < 4; j++) {
                *(uint4*)&As[r*72 + c + j*8] = *(const uint4*)(Ab + k0 + j*8);
                *(uint4*)&Ws[r*72 + c + j*8] = *(const uint4*)(Wp + k0 + j*8);
            }
        }
        __syncthreads();
        #pragma unroll
        for (int ks = 0; ks < 64; ks += 32) {
            s16x8 a[4], b[4];
            #pragma unroll
            for (int m = 0; m < 4; m++)
                a[m] = *(const s16x8*)&As[(wm*64 + m*16 + fr)*72 + ks + fq*8];
            #pragma unroll
            for (int n = 0; n < 4; n++)
                b[n] = *(const s16x8*)&Ws[(wn*64 + n*16 + fr)*72 + ks + fq*8];
            #pragma unroll
            for (int m = 0; m < 4; m++)
                #pragma unroll
                for (int n = 0; n < 4; n++)
                    acc[m][n] = __builtin_amdgcn_mfma_f32_16x16x32_bf16(a[m], b[n], acc[m][n], 0, 0, 0);
        }
    }
    float* Co = (float*)Cv;
    unsigned short* Cb = (unsigned short*)Cv;
    #pragma unroll
    for (int m = 0; m < 4; m++) {
        const int r0 = bm + wm*64 + m*16 + fq*4;
        #pragma unroll
        for (int n = 0; n < 4; n++) {
            const int col = bn + wn*64 + n*16 + fr;
            const float bsv = bias[col];
            #pragma unroll
            for (int j = 0; j < 4; j++) {
                float v = acc[m][n][j] + bsv;
                if (RELU) v = fmaxf(v, 0.f);
                if (OBF16) Cb[(size_t)(r0 + j) * N + col] = f2bf(v);
                else       Co[(size_t)(r0 + j) * N + col] = v;
            }
        }
    }
}

// ---------------------------------------------------------------------------
// bf16 MFMA NT GEMM, BM=128 BN=64 (round-3-verified structure, all-bf16).
// Used for the N=256 / M=19200 GEMMs where grid occupancy favors BN=64.
// ---------------------------------------------------------------------------
template<int RELU, int OBF16>
__global__ __launch_bounds__(256) void gemm_bf16_64(
    const unsigned short* __restrict__ A, const unsigned short* __restrict__ W,
    const float* __restrict__ bias, void* __restrict__ Cv, int M, int N, int K)
{
    __shared__ unsigned short As[128 * 72];
    __shared__ unsigned short Ws[64 * 72];
    const int tid = threadIdx.x;
    const int bm = blockIdx.y * 128;
    const int bn = blockIdx.x * 64;
    const int ar = tid >> 1;
    const int ac = (tid & 1) * 32;
    const int wr = tid >> 2;
    const int wc = (tid & 3) * 16;
    const unsigned short* Ap = A + (size_t)(bm + ar) * K + ac;
    const unsigned short* Wp = W + (size_t)(bn + wr) * K + wc;
    const int lane = tid & 63;
    const int wid  = tid >> 6;
    const int wm = wid >> 1, wn = wid & 1;
    const int fr = lane & 15;
    const int fq = lane >> 4;
    f32x4 acc[4][2];
    #pragma unroll
    for (int m = 0; m < 4; m++)
        #pragma unroll
        for (int n = 0; n < 2; n++)
            acc[m][n] = (f32x4){0.f, 0.f, 0.f, 0.f};

    for (int k0 = 0; k0 < K; k0 += 64) {
        __syncthreads();
        #pragma unroll
        for (int j = 0; j < 4; j++)
            *(uint4*)&As[ar*72 + ac + j*8] = *(const uint4*)(Ap + k0 + j*8);
        #pragma unroll
        for (int j = 0; j < 2; j++)
            *(uint4*)&Ws[wr*72 + wc + j*8] = *(const uint4*)(Wp + k0 + j*8);
        __syncthreads();
        #pragma unroll
        for (int ks = 0; ks < 64; ks += 32) {
            s16x8 a0 = *(const s16x8*)&As[(wm*64 +  0 + fr)*72 + ks + fq*8];
            s16x8 a1 = *(const s16x8*)&As[(wm*64 + 16 + fr)*72 + ks + fq*8];
            s16x8 a2 = *(const s16x8*)&As[(wm*64 + 32 + fr)*72 + ks + fq*8];
            s16x8 a3 = *(const s16x8*)&As[(wm*64 + 48 + fr)*72 + ks + fq*8];
            s16x8 b0 = *(const s16x8*)&Ws[(wn*32 +  0 + fr)*72 + ks + fq*8];
            s16x8 b1 = *(const s16x8*)&Ws[(wn*32 + 16 + fr)*72 + ks + fq*8];
            acc[0][0] = __builtin_amdgcn_mfma_f32_16x16x32_bf16(a0, b0, acc[0][0], 0, 0, 0);
            acc[0][1] = __builtin_amdgcn_mfma_f32_16x16x32_bf16(a0, b1, acc[0][1], 0, 0, 0);
            acc[1][0] = __builtin_amdgcn_mfma_f32_16x16x32_bf16(a1, b0, acc[1][0], 0, 0, 0);
            acc[1][1] = __builtin_amdgcn_mfma_f32_16x16x32_bf16(a1, b1, acc[1][1], 0, 0, 0);
            acc[2][0] = __builtin_amdgcn_mfma_f32_16x16x32_bf16(a2, b0, acc[2][0], 0, 0, 0);
            acc[2][1] = __builtin_amdgcn_mfma_f32_16x16x32_bf16(a2, b1, acc[2][1], 0, 0, 0);
            acc[3][0] = __builtin_amdgcn_mfma_f32_16x16x32_bf16(a3, b0, acc[3][0], 0, 0, 0);
            acc[3][1] = __builtin_amdgcn_mfma_f32_16x16x32_bf16(a3, b1, acc[3][1], 0, 0, 0);
        }
    }
    float* Co = (float*)Cv;
    unsigned short* Cb = (unsigned short*)Cv;
    #pragma unroll
    for (int m = 0; m < 4; m++) {
        const int r0 = bm + wm*64 + m*16 + fq*4;
        #pragma unroll
        for (int n = 0; n < 2; n++) {
            const int col = bn + wn*32 + n*16 + fr;
            const float bsv = bias[col];
            #pragma unroll
            for (int j = 0; j < 4; j++) {
                float v = acc[m][n][j] + bsv;
                if (RELU) v = fmaxf(v, 0.f);
                if (OBF16) Cb[(size_t)(r0 + j) * N + col] = f2bf(v);
                else       Co[(size_t)(r0 + j) * N + col] = v;
            }
        }
    }
}

// ---------------------------------------------------------------------------
// MFMA self-attention (unchanged, verified rounds 5/8).
// ---------------------------------------------------------------------------
#define KS_ST 40
#define VT_ST 328
#define PB_ST 40
__global__ __launch_bounds__(256) void attn_mfma(
    const unsigned short* __restrict__ qkv, unsigned short* __restrict__ o)
{
    const int h  = blockIdx.x & 7;
    const int bp = blockIdx.x >> 3;   // b*16+p
    const int p  = bp & 15;
    const int b  = bp >> 4;
    __shared__ unsigned short Ks[304 * KS_ST];
    __shared__ unsigned short Vt[32 * VT_ST];
    __shared__ unsigned short Pb[4][16 * PB_ST];
    const int tid = threadIdx.x;
    const size_t qbase = ((size_t)b * 4800 + p) * 768 + h * 32; // + q*16*768
    for (int k = tid; k < 304; k += 256) {
        uint4 v0, v1, v2, v3;
        if (k < 300) {
            const unsigned short* src = qkv + qbase + (size_t)k * (16*768) + 256;
            v0 = *(const uint4*)(src);      v1 = *(const uint4*)(src + 8);
            v2 = *(const uint4*)(src + 16); v3 = *(const uint4*)(src + 24);
        } else {
            v0 = v1 = v2 = v3 = make_uint4(0u, 0u, 0u, 0u);
        }
        *(uint4*)&Ks[k*KS_ST +  0] = v0; *(uint4*)&Ks[k*KS_ST +  8] = v1;
        *(uint4*)&Ks[k*KS_ST + 16] = v2; *(uint4*)&Ks[k*KS_ST + 24] = v3;
    }
    for (int k = tid; k < 320; k += 256) {
        union { uint4 v[4]; unsigned short s[32]; } t;
        if (k < 300) {
            const unsigned short* src = qkv + qbase + (size_t)k * (16*768) + 512;
            t.v[0] = *(const uint4*)(src);      t.v[1] = *(const uint4*)(src + 8);
            t.v[2] = *(const uint4*)(src + 16); t.v[3] = *(const uint4*)(src + 24);
        } else {
            t.v[0] = t.v[1] = t.v[2] = t.v[3] = make_uint4(0u, 0u, 0u, 0u);
        }
        #pragma unroll
        for (int d = 0; d < 32; d++) Vt[d*VT_ST + k] = t.s[d];
    }
    __syncthreads();

    const int wid = tid >> 6, lane = tid & 63;
    const int fr = lane & 15, fq = lane >> 4;
    const float scale = 0.17677669529663689f; // 1/sqrt(32)
    unsigned short* Pw = &Pb[wid][0];

    for (int qt = wid; qt < 19; qt += 4) {
        int qr = qt*16 + fr; if (qr > 299) qr = 299;
        const s16x8 aq = *(const s16x8*)(qkv + qbase + (size_t)qr * (16*768) + fq*8);
        f32x4 s[19];
        #pragma unroll
        for (int t = 0; t < 19; t++) {
            s16x8 bk = *(const s16x8*)&Ks[(t*16 + fr)*KS_ST + fq*8];
            s[t] = __builtin_amdgcn_mfma_f32_16x16x32_bf16(aq, bk, (f32x4){0.f,0.f,0.f,0.f}, 0, 0, 0);
        }
        if (fr >= 12) s[18] = (f32x4){-1e30f, -1e30f, -1e30f, -1e30f}; // keys >= 300
        float mx[4], l[4];
        #pragma unroll
        for (int j = 0; j < 4; j++) {
            float m = s[0][j];
            #pragma unroll
            for (int t = 1; t < 19; t++) m = fmaxf(m, s[t][j]);
            #pragma unroll
            for (int msk = 1; msk < 16; msk <<= 1) m = fmaxf(m, __shfl_xor(m, msk));
            mx[j] = m;
        }
        #pragma unroll
        for (int j = 0; j < 4; j++) {
            float sum = 0.f;
            #pragma unroll
            for (int t = 0; t < 19; t++) {
                const float e = __expf((s[t][j] - mx[j]) * scale);
                s[t][j] = e;
                sum += e;
            }
            #pragma unroll
            for (int msk = 1; msk < 16; msk <<= 1) sum += __shfl_xor(sum, msk);
            l[j] = sum;
        }
        f32x4 oa0 = (f32x4){0.f,0.f,0.f,0.f}, oa1 = (f32x4){0.f,0.f,0.f,0.f};
        #pragma unroll
        for (int st = 0; st < 10; st++) {
            #pragma unroll
            for (int j = 0; j < 4; j++) {
                Pw[(fq*4 + j)*PB_ST + fr]      = f2bf(s[2*st][j]);
                Pw[(fq*4 + j)*PB_ST + 16 + fr] = (2*st + 1 < 19) ? f2bf(s[2*st+1][j])
                                                                 : (unsigned short)0;
            }
            const s16x8 ap = *(const s16x8*)&Pw[fr*PB_ST + fq*8];
            const s16x8 b0 = *(const s16x8*)&Vt[fr*VT_ST + st*32 + fq*8];
            const s16x8 b1 = *(const s16x8*)&Vt[(16 + fr)*VT_ST + st*32 + fq*8];
            oa0 = __builtin_amdgcn_mfma_f32_16x16x32_bf16(ap, b0, oa0, 0, 0, 0);
            oa1 = __builtin_amdgcn_mfma_f32_16x16x32_bf16(ap, b1, oa1, 0, 0, 0);
        }
        #pragma unroll
        for (int j = 0; j < 4; j++) {
            const int q = qt*16 + fq*4 + j;
            if (q < 300) {
                const float inv = 1.0f / l[j];
                unsigned short* op = o + ((size_t)(b*4800 + q*16 + p))*256 + h*32;
                op[fr]      = f2bf(oa0[j] * inv);
                op[16 + fr] = f2bf(oa1[j] * inv);
            }
        }
    }
}

// ---------------------------------------------------------------------------
// Fused add + LayerNorm; optional bf16 side-output (with optional +qp) so the
// consuming GEMM gets a pre-converted A operand (numerically identical to the
// old in-staging conversion).
// ---------------------------------------------------------------------------
template<int EMIT, int HAS_QP>
__global__ __launch_bounds__(256) void ln_add_kernel(
    const float* __restrict__ a, const float* __restrict__ b2,
    const float* __restrict__ g, const float* __restrict__ be,
    const float* __restrict__ qp,
    float* __restrict__ out, unsigned short* __restrict__ outb)
{
    const int row = blockIdx.x;
    const int c = threadIdx.x;
    const size_t idx = (size_t)row * 256 + c;
    const float x = a[idx] + b2[idx];
    float s = x, s2 = x * x;
    #pragma unroll
    for (int m = 32; m >= 1; m >>= 1) {
        s  += __shfl_xor(s, m);
        s2 += __shfl_xor(s2, m);
    }
    __shared__ float ws1[4], ws2[4];
    const int w = threadIdx.x >> 6;
    if ((threadIdx.x & 63) == 0) { ws1[w] = s; ws2[w] = s2; }
    __syncthreads();
    s  = ws1[0] + ws1[1] + ws1[2] + ws1[3];
    s2 = ws2[0] + ws2[1] + ws2[2] + ws2[3];
    const float mean = s * (1.f/256.f);
    const float var  = s2 * (1.f/256.f) - mean * mean;
    const float r = rsqrtf(var + 1e-5f);
    const float y = (x - mean) * r * g[c] + be[c];
    out[idx] = y;
    if (EMIT) {
        const float z = HAS_QP ? y + qp[idx] : y;
        outb[idx] = f2bf(z);
    }
}

// ---------------------------------------------------------------------------
// MSDA sampling, wave-per-(row,head), task-parallel (unchanged, verified r8).
// ---------------------------------------------------------------------------
__global__ __launch_bounds__(256) void msda_kernel(
    const unsigned short* __restrict__ value,  // (B*LIN, 256) bf16
    const float* __restrict__ offsattw,        // (B*4800, 384) fp32
    const float* __restrict__ refp,            // (B*4800, 4, 2) fp32
    unsigned short* __restrict__ samp)         // (B*4800, 256) bf16
{
    const int task = blockIdx.x * 4 + (threadIdx.x >> 6);  // (row, h)
    const int row = task >> 3;
    const int h   = task & 7;
    const int l   = threadIdx.x & 63;
    const int s   = l >> 2;
    const int cq  = l & 3;

    const float* base = offsattw + (size_t)row * 384;
    const float lg = base[256 + h*16 + s];
    float mxv = lg;
    #pragma unroll
    for (int m = 4; m < 64; m <<= 1) mxv = fmaxf(mxv, __shfl_xor(mxv, m));
    const float e = __expf(lg - mxv);
    float ssum = e;
    #pragma unroll
    for (int m = 4; m < 64; m <<= 1) ssum += __shfl_xor(ssum, m);
    const float w_att = e * (1.0f / ssum);
    const int lv = s >> 2;
    const int Wtab[4]  = {128, 64, 32, 16};
    const int STtab[4] = {0, 16384, 20480, 21504};
    const int W = Wtab[lv];
    const float fW = (float)W;
    const float ox = base[h*32 + s*2];
    const float oy = base[h*32 + s*2 + 1];
    const float rx = refp[(size_t)row*8 + lv*2];
    const float ry = refp[(size_t)row*8 + lv*2 + 1];
    const float x = (rx + ox / fW) * fW - 0.5f;
    const float y = (ry + oy / fW) * fW - 0.5f;
    const float x0f = floorf(x), y0f = floorf(y);
    const float wx = x - x0f, wy = y - y0f;
    const int xi = (int)x0f + (cq & 1);
    const int yi = (int)y0f + (cq >> 1);
    const bool valid = (xi >= 0) & (xi < W) & (yi >= 0) & (yi < W);
    const int xc = min(max(xi, 0), W - 1);
    const int yc = min(max(yi, 0), W - 1);
    const float wxs = (cq & 1)  ? wx : 1.f - wx;
    const float wys = (cq >> 1) ? wy : 1.f - wy;
    const float wgt = valid ? (w_att * wxs * wys) : 0.f;
    const unsigned boff = (unsigned)(STtab[lv] + yc * W + xc) * 512u + (unsigned)h * 64u;

    const char* vb = (const char*)(value + (size_t)(row / LQ) * LIN_TOT * 256);
    float acc[8] = {0.f, 0.f, 0.f, 0.f, 0.f, 0.f, 0.f, 0.f};
    #pragma unroll
    for (int g = 0; g < 4; g++) {
        const int src = g * 16 + s;
        const unsigned a = (unsigned)__shfl((int)boff, src);
        const float    w = __shfl(wgt, src);
        const uint4 v4 = *(const uint4*)(vb + a + cq * 16);
        const unsigned u[4] = {v4.x, v4.y, v4.z, v4.w};
        #pragma unroll
        for (int j = 0; j < 4; j++) {
            acc[2*j]   += w * __uint_as_float(u[j] << 16);
            acc[2*j+1] += w * __uint_as_float(u[j] & 0xFFFF0000u);
        }
    }
    #pragma unroll
    for (int m = 4; m < 64; m <<= 1)
        #pragma unroll
        for (int j = 0; j < 8; j++)
            acc[j] += __shfl_xor(acc[j], m);
    if (s == 0) {
        union { unsigned short sh[8]; uint4 v; } pk;
        #pragma unroll
        for (int j = 0; j < 8; j++) pk.sh[j] = f2bf(acc[j]);
        *(uint4*)(samp + (size_t)row * 256 + h * 32 + cq * 8) = pk.v;
    }
}

// ---------------------------------------------------------------------------
// Workspace layout (float units), lifetime reuse. Total 46,055,808 fl =184 MB.
//   A [0, 11141120):          qkv(bf16) -> value(bf16) -> hbuf(bf16)
//   B [11141120,+4915200):    o1/samp bf16 -> f2 fp32
//   C [16056320,+4915200):    o2 -> t2
//   D [20971520,+4915200):    x1
//   E [25886720,+7372800):    offsattw
//   F [33259520,+4915200):    x2
//   G [38174720,+2457600):    xq  bf16
//   H [40632320,+2457600):    x2b bf16
//   I [43089920,+2457600):    tgtb bf16
//   K [45547520,+507904):     weights bf16
//   L [46055424,+384):        Wb fp32 (merged off|attw bias)
// (src is consumed fp32 directly by the value GEMM's AFP32 staging — the
//  round-9 srcb pre-cast under-counted elements (bug) and is removed.)
// ---------------------------------------------------------------------------
extern "C" void kernel_launch(void* const* d_in, const int* in_sizes, int n_in,
                              void* d_out, int out_size, void* d_ws, size_t ws_size,
                              hipStream_t stream)
{
    const float* tgt        = (const float*)d_in[0];
    const float* query_pos  = (const float*)d_in[1];
    const float* refp       = (const float*)d_in[2];
    const float* src        = (const float*)d_in[3];
    const float* inproj_w   = (const float*)d_in[6];
    const float* inproj_b   = (const float*)d_in[7];
    const float* outproj_w  = (const float*)d_in[8];
    const float* outproj_b  = (const float*)d_in[9];
    const float* ln_inter_g = (const float*)d_in[10];
    const float* ln_inter_b = (const float*)d_in[11];
    const float* ln_cross_g = (const float*)d_in[12];
    const float* ln_cross_b = (const float*)d_in[13];
    const float* ln3_g      = (const float*)d_in[14];
    const float* ln3_b      = (const float*)d_in[15];
    const float* off_w      = (const float*)d_in[16];
    const float* off_b      = (const float*)d_in[17];
    const float* attw_w     = (const float*)d_in[18];
    const float* attw_b     = (const float*)d_in[19];
    const float* val_w      = (const float*)d_in[20];
    const float* val_b      = (const float*)d_in[21];
    const float* mout_w     = (const float*)d_in[22];
    const float* mout_b     = (const float*)d_in[23];
    const float* lin1_w     = (const float*)d_in[24];
    const float* lin1_b     = (const float*)d_in[25];
    const float* lin2_w     = (const float*)d_in[26];
    const float* lin2_b     = (const float*)d_in[27];

    float* ws = (float*)d_ws;
    unsigned short* qkv   = (unsigned short*)ws;              // A
    unsigned short* value = (unsigned short*)ws;              // A
    unsigned short* hbuf  = (unsigned short*)ws;              // A
    unsigned short* o1    = (unsigned short*)(ws + 11141120); // B
    unsigned short* samp  = o1;
    float* f2      = ws + 11141120;                           // B
    float* o2      = ws + 16056320;                           // C
    float* t2      = o2;
    float* x1      = ws + 20971520;                           // D
    float* offsattw= ws + 25886720;                           // E
    float* x2      = ws + 33259520;                           // F
    unsigned short* xq   = (unsigned short*)(ws + 38174720);  // G
    unsigned short* x2b  = (unsigned short*)(ws + 40632320);  // H
    unsigned short* tgtb = (unsigned short*)(ws + 43089920);  // I
    unsigned short* wb   = (unsigned short*)(ws + 45547520);  // K
    unsigned short* wb_inproj = wb;            // 196608 shorts
    unsigned short* wb_outproj= wb + 196608;   //  65536
    unsigned short* wb_m      = wb + 262144;   //  98304 (off 65536 | attw 32768)
    unsigned short* wb_val    = wb + 360448;   //  65536
    unsigned short* wb_mout   = wb + 425984;   //  65536
    unsigned short* wb_lin1   = wb + 491520;   // 262144
    unsigned short* wb_lin2   = wb + 753664;   // 262144
    float* Wb      = ws + 46055424;                           // L
    float* outp    = (float*)d_out;

    // 0) one-time conversions + merged bias copy
    {
        W8x8 p;
        p.w[0] = { inproj_w,  wb_inproj,  196608/8 };
        p.w[1] = { outproj_w, wb_outproj,  65536/8 };
        p.w[2] = { off_w,     wb_m,        65536/8 };
        p.w[3] = { attw_w,    wb_m+65536,  32768/8 };
        p.w[4] = { val_w,     wb_val,      65536/8 };
        p.w[5] = { mout_w,    wb_mout,     65536/8 };
        p.w[6] = { lin1_w,    wb_lin1,    262144/8 };
        p.w[7] = { lin2_w,    wb_lin2,    262144/8 };
        cast_w8<<<dim3(32, 8), 256, 0, stream>>>(p);
    }
    cast_bf16<<<2400, 256, 0, stream>>>(tgt, tgtb, 4915200/8);
    hipMemcpyAsync(Wb,       off_b,  256u * 4, hipMemcpyDeviceToDevice, stream);
    hipMemcpyAsync(Wb + 256, attw_b, 128u * 4, hipMemcpyDeviceToDevice, stream);

    // 1) qkv = tgt @ inproj^T + b  -> bf16
    gemm_bf16_128<0,1,0><<<dim3(6,150), 256, 0, stream>>>(tgtb, wb_inproj, inproj_b, qkv, NROW, 768, 256);
    // 2) self-attention (MFMA) -> bf16 o1
    attn_mfma<<<512, 256, 0, stream>>>(qkv, o1);
    // 3) outproj -> fp32 o2
    gemm_bf16_64<0,0><<<dim3(4,150), 256, 0, stream>>>(o1, wb_outproj, outproj_b, o2, NROW, 256, 256);
    // 4) x1 = LN(tgt + o2); also emit xq = bf16(x1 + query_pos)
    ln_add_kernel<1,1><<<NROW, 256, 0, stream>>>(tgt, o2, ln_inter_g, ln_inter_b, query_pos, x1, xq);
    // 5) offs|attw = xq @ Wm^T + Wb -> fp32
    gemm_bf16_128<0,0,0><<<dim3(3,150), 256, 0, stream>>>(xq, wb_m, Wb, offsattw, NROW, 384, 256);
    // 6) value projection: fp32 src converted in staging (AFP32) -> bf16 value
    gemm_bf16_128<0,1,1><<<dim3(2,680), 256, 0, stream>>>(src, wb_val, val_b, value, B_DIM * LIN_TOT, 256, 256);
    // 7) deformable sampling (wave per (row,head))
    msda_kernel<<<38400, 256, 0, stream>>>(value, offsattw, refp, samp);
    // 8) mout -> fp32 t2
    gemm_bf16_64<0,0><<<dim3(4,150), 256, 0, stream>>>(samp, wb_mout, mout_b, t2, NROW, 256, 256);
    // 9) x2 = LN(x1 + t2); also emit x2b = bf16(x2)
    ln_add_kernel<1,0><<<NROW, 256, 0, stream>>>(x1, t2, ln_cross_g, ln_cross_b, nullptr, x2, x2b);
    // 10) FFN up + ReLU -> bf16 hbuf
    gemm_bf16_128<1,1,0><<<dim3(8,150), 256, 0, stream>>>(x2b, wb_lin1, lin1_b, hbuf, NROW, DFF, 256);
    // 11) FFN down -> fp32 f2
    gemm_bf16_64<0,0><<<dim3(4,150), 256, 0, stream>>>(hbuf, wb_lin2, lin2_b, f2, NROW, 256, DFF);
    // 12) out = LN(x2 + f2)
    ln_add_kernel<0,0><<<NROW, 256, 0, stream>>>(x2, f2, ln3_g, ln3_b, nullptr, outp, nullptr);
}